// Round 1
// baseline (628.388 us; speedup 1.0000x reference)
//
#include <hip/hip_runtime.h>
#include <hip/hip_bf16.h>

#define H_DIM 2048
#define T_TOK 2048
#define E_NUM 16
#define I_DIM 1024
#define TOPK  4

typedef short short8v __attribute__((ext_vector_type(8)));
typedef float f32x4v __attribute__((ext_vector_type(4)));
typedef unsigned short u16;
typedef unsigned int u32;

// ---------- ws layout (bytes) ----------
constexpr size_t OFF_XB   = 0;                                  // 2048*2048*2   = 8 MiB
constexpr size_t OFF_WGT  = OFF_XB   + (size_t)T_TOK*H_DIM*2;   // 16*2048*1024*2 = 64 MiB (later aliased by wd_t)
constexpr size_t OFF_WUT  = OFF_WGT  + (size_t)E_NUM*H_DIM*I_DIM*2;
constexpr size_t OFF_ABUF = OFF_WUT  + (size_t)E_NUM*H_DIM*I_DIM*2; // 8192*1024*2 = 16 MiB
constexpr size_t OFF_SEL  = OFF_ABUF + (size_t)T_TOK*TOPK*I_DIM*2;
constexpr size_t OFF_WTS  = OFF_SEL  + (size_t)T_TOK*TOPK*4;
constexpr size_t OFF_CNT  = OFF_WTS  + (size_t)T_TOK*TOPK*4;
constexpr size_t OFF_OFFS = OFF_CNT  + 128;
constexpr size_t OFF_CURS = OFF_OFFS + 128;
constexpr size_t OFF_RTOK = OFF_CURS + 128;
constexpr size_t OFF_RWT  = OFF_RTOK + (size_t)T_TOK*TOPK*4;
constexpr size_t WS_NEED  = OFF_RWT  + (size_t)T_TOK*TOPK*4;

// ---------- helpers ----------
__device__ __forceinline__ u16 f2b(float f) {   // fp32 -> bf16, round-nearest-even
  u32 u = __builtin_bit_cast(u32, f);
  u32 r = (u + 0x7FFFu + ((u >> 16) & 1u)) >> 16;
  return (u16)r;
}

__device__ __forceinline__ void gld16(const void* g, void* l) {
  __builtin_amdgcn_global_load_lds(
      (const __attribute__((address_space(1))) u32*)g,
      (__attribute__((address_space(3))) u32*)l, 16, 0, 0);
}

// ---------- fp32 -> bf16 (x) ----------
__global__ __launch_bounds__(256) void cvt_x_kernel(const float* __restrict__ src,
                                                    u16* __restrict__ dst) {
  int i = blockIdx.x * 256 + threadIdx.x;        // over (T*H)/8 groups
  const float4* s = (const float4*)src + (size_t)i * 2;
  float4 a = s[0], b = s[1];
  uint4 o;
  o.x = (u32)f2b(a.x) | ((u32)f2b(a.y) << 16);
  o.y = (u32)f2b(a.z) | ((u32)f2b(a.w) << 16);
  o.z = (u32)f2b(b.x) | ((u32)f2b(b.y) << 16);
  o.w = (u32)f2b(b.z) | ((u32)f2b(b.w) << 16);
  ((uint4*)dst)[i] = o;
}

// ---------- fp32 (R,C) -> bf16 (C,R) transpose-convert, per expert ----------
__global__ __launch_bounds__(256) void tconv_kernel(const float* __restrict__ src,
                                                    u16* __restrict__ dst,
                                                    int R, int C) {
  __shared__ u16 lds[64 * 68];                   // stored transposed: lds[c][r]
  int e = blockIdx.z;
  int rb = blockIdx.y * 64, cb = blockIdx.x * 64;
  const float* se = src + (size_t)e * R * C;
  u16* de = dst + (size_t)e * R * C;
  #pragma unroll
  for (int it = 0; it < 16; ++it) {
    int idx = it * 256 + threadIdx.x;            // 4096 elements
    int r = idx >> 6, c = idx & 63;
    float v = se[(size_t)(rb + r) * C + cb + c]; // coalesced along c
    lds[c * 68 + r] = f2b(v);
  }
  __syncthreads();
  #pragma unroll
  for (int it = 0; it < 4; ++it) {
    int v = it * 256 + threadIdx.x;              // 1024 groups of 4
    int c = v >> 4, r4 = (v & 15) * 4;
    uint2 val = *(const uint2*)&lds[c * 68 + r4];
    *(uint2*)&de[(size_t)(cb + c) * R + rb + r4] = val;   // coalesced along r
  }
}

// ---------- router: fp32 logits, top-4, softmax ----------
__global__ __launch_bounds__(256) void router_kernel(const float* __restrict__ x,
                                                     const float* __restrict__ rw,
                                                     float* __restrict__ logits,
                                                     int* __restrict__ sel,
                                                     float* __restrict__ wts) {
  int w = threadIdx.x >> 6, lane = threadIdx.x & 63;
  int t = blockIdx.x * 4 + w;
  const float* xt = x + (size_t)t * H_DIM;
  float le[E_NUM];
  float mine = 0.f;
  #pragma unroll
  for (int e = 0; e < E_NUM; ++e) {
    const float* we = rw + (size_t)e * H_DIM;
    float s = 0.f;
    for (int h = lane; h < H_DIM; h += 64) s += xt[h] * we[h];
    #pragma unroll
    for (int off = 32; off; off >>= 1) s += __shfl_xor(s, off);
    le[e] = s;
    if (lane == e) mine = s;
  }
  if (lane < E_NUM) logits[(size_t)t * E_NUM + lane] = mine;
  // top-4, strict > so ties pick lower index (matches jax.lax.top_k)
  int taken = 0;
  float tv[TOPK]; int ti[TOPK];
  #pragma unroll
  for (int k = 0; k < TOPK; ++k) {
    float bv = -1e30f; int bi = 0;
    #pragma unroll
    for (int e = 0; e < E_NUM; ++e) {
      bool ok = !(taken & (1 << e));
      if (ok && le[e] > bv) { bv = le[e]; bi = e; }
    }
    taken |= (1 << bi); tv[k] = bv; ti[k] = bi;
  }
  float m = tv[0];
  float ew[TOPK]; float ssum = 0.f;
  #pragma unroll
  for (int k = 0; k < TOPK; ++k) { ew[k] = __expf(tv[k] - m); ssum += ew[k]; }
  if (lane == 0) {
    float inv = 1.f / ssum;
    #pragma unroll
    for (int k = 0; k < TOPK; ++k) {
      sel[t * TOPK + k] = ti[k];
      wts[t * TOPK + k] = ew[k] * inv;
    }
  }
}

// ---------- grouping ----------
__global__ void hist_kernel(const int* __restrict__ sel, int* __restrict__ cnt) {
  int p = blockIdx.x * 256 + threadIdx.x;
  if (p < T_TOK * TOPK) atomicAdd(&cnt[sel[p]], 1);
}

__global__ void prefix_kernel(const int* __restrict__ cnt, int* __restrict__ offs,
                              int* __restrict__ curs) {
  if (threadIdx.x == 0) {
    int a = 0;
    for (int e = 0; e < E_NUM; ++e) { offs[e] = a; curs[e] = a; a += cnt[e]; }
    offs[E_NUM] = a;
  }
}

__global__ void scatter_kernel(const int* __restrict__ sel, const float* __restrict__ wts,
                               int* __restrict__ curs, int* __restrict__ rtok,
                               float* __restrict__ rwt) {
  int p = blockIdx.x * 256 + threadIdx.x;
  if (p >= T_TOK * TOPK) return;
  int e = sel[p];
  int pos = atomicAdd(&curs[e], 1);
  rtok[pos] = p >> 2;
  rwt[pos] = wts[p];
}

// ---------- GEMM1: fused gate+up -> silu(g)*u*wt -> Abuf (bf16) ----------
// A: gathered x rows (M=128 tile, K=H). Bg/Bu: transposed weights [e][i][h] so
// per-lane MFMA fragments are 8 contiguous k. 16B-slot XOR(row&7) swizzle on
// LDS: linear dest + inverse-swizzled global source (rule #21).
__global__ __launch_bounds__(256) void gemm1_kernel(
    const u16* __restrict__ xb, const u16* __restrict__ wg, const u16* __restrict__ wu,
    const int* __restrict__ cnt, const int* __restrict__ offs,
    const int* __restrict__ rtok, const float* __restrict__ rwt,
    u16* __restrict__ abuf) {
  int e = blockIdx.z;
  int cntE = cnt[e];
  int m0 = blockIdx.y * 128;
  if (m0 >= cntE) return;
  int n0 = blockIdx.x * 128;
  int base = offs[e];

  __shared__ alignas(16) u16 As[128 * 64];
  __shared__ alignas(16) u16 Bg[128 * 64];
  __shared__ alignas(16) u16 Bu[128 * 64];
  __shared__ int tokloc[128];
  __shared__ float wtloc[128];

  int tid = threadIdx.x;
  for (int i = tid; i < 128; i += 256) {
    int p = m0 + i;
    int pp = (p < cntE) ? p : (cntE - 1);
    tokloc[i] = rtok[base + pp];
    wtloc[i] = (p < cntE) ? rwt[base + pp] : 0.f;
  }
  __syncthreads();

  int lane = tid & 63;
  int w = tid >> 6;
  int wr = (w >> 1) * 64, wc = (w & 1) * 64;
  int ln15 = lane & 15, g4 = lane >> 4;

  const u16* wge = wg + ((size_t)e * I_DIM + n0) * H_DIM;
  const u16* wue = wu + ((size_t)e * I_DIM + n0) * H_DIM;

  // staging descriptors (linear LDS dest, inverse-swizzled global source)
  const u16* aptr[4]; const u16* gptr[4]; const u16* uptr[4]; int soff[4];
  #pragma unroll
  for (int it = 0; it < 4; ++it) {
    int s = it * 256 + tid;
    int row = s >> 3;
    int c16 = (s & 7) ^ (row & 7);
    soff[it] = s * 16;
    aptr[it] = xb + (size_t)tokloc[row] * H_DIM + c16 * 8;
    gptr[it] = wge + (size_t)row * H_DIM + c16 * 8;
    uptr[it] = wue + (size_t)row * H_DIM + c16 * 8;
  }

  f32x4v accg[4][4], accu[4][4];
  #pragma unroll
  for (int m = 0; m < 4; ++m)
    #pragma unroll
    for (int n = 0; n < 4; ++n) { accg[m][n] = f32x4v{0,0,0,0}; accu[m][n] = f32x4v{0,0,0,0}; }

  int xk[2] = { g4 ^ (lane & 7), (4 + g4) ^ (lane & 7) };

  for (int kb = 0; kb < H_DIM; kb += 64) {
    #pragma unroll
    for (int it = 0; it < 4; ++it) {
      gld16(aptr[it] + kb, (char*)As + soff[it]);
      gld16(gptr[it] + kb, (char*)Bg + soff[it]);
      gld16(uptr[it] + kb, (char*)Bu + soff[it]);
    }
    __syncthreads();
    #pragma unroll
    for (int kk = 0; kk < 2; ++kk) {
      short8v a[4], bg[4], bu[4];
      int xo = xk[kk] * 16;
      #pragma unroll
      for (int m = 0; m < 4; ++m) {
        int row = wr + m * 16 + ln15;
        a[m] = *(const short8v*)((const char*)As + row * 128 + xo);
      }
      #pragma unroll
      for (int n = 0; n < 4; ++n) {
        int row = wc + n * 16 + ln15;
        bg[n] = *(const short8v*)((const char*)Bg + row * 128 + xo);
        bu[n] = *(const short8v*)((const char*)Bu + row * 128 + xo);
      }
      #pragma unroll
      for (int m = 0; m < 4; ++m)
        #pragma unroll
        for (int n = 0; n < 4; ++n) {
          accg[m][n] = __builtin_amdgcn_mfma_f32_16x16x32_bf16(a[m], bg[n], accg[m][n], 0, 0, 0);
          accu[m][n] = __builtin_amdgcn_mfma_f32_16x16x32_bf16(a[m], bu[n], accu[m][n], 0, 0, 0);
        }
    }
    __syncthreads();
  }

  // epilogue: silu(g)*u*wt -> bf16
  #pragma unroll
  for (int m = 0; m < 4; ++m) {
    #pragma unroll
    for (int r = 0; r < 4; ++r) {
      int row = wr + m * 16 + g4 * 4 + r;
      if (m0 + row < cntE) {
        float wt = wtloc[row];
        size_t orow = (size_t)(base + m0 + row) * I_DIM + n0 + wc;
        #pragma unroll
        for (int n = 0; n < 4; ++n) {
          float g = accg[m][n][r], u = accu[m][n][r];
          float aa = g / (1.f + __expf(-g)) * u * wt;
          abuf[orow + n * 16 + ln15] = f2b(aa);
        }
      }
    }
  }
}

// ---------- GEMM2: Abuf @ w_down -> atomic-add into out ----------
__global__ __launch_bounds__(256) void gemm2_kernel(
    const u16* __restrict__ abuf, const u16* __restrict__ wd,
    const int* __restrict__ cnt, const int* __restrict__ offs,
    const int* __restrict__ rtok, float* __restrict__ out) {
  int e = blockIdx.z;
  int cntE = cnt[e];
  int m0 = blockIdx.y * 128;
  if (m0 >= cntE) return;
  int n0 = blockIdx.x * 128;
  int base = offs[e];

  __shared__ alignas(16) u16 As[128 * 64];
  __shared__ alignas(16) u16 Bd[128 * 64];
  __shared__ int tokloc[128];

  int tid = threadIdx.x;
  for (int i = tid; i < 128; i += 256) {
    int p = m0 + i;
    int pp = (p < cntE) ? p : (cntE - 1);
    tokloc[i] = rtok[base + pp];
  }
  __syncthreads();

  int lane = tid & 63;
  int w = tid >> 6;
  int wr = (w >> 1) * 64, wc = (w & 1) * 64;
  int ln15 = lane & 15, g4 = lane >> 4;

  const u16* wde = wd + ((size_t)e * H_DIM + n0) * I_DIM;

  const u16* aptr[4]; const u16* bptr[4]; int soff[4];
  #pragma unroll
  for (int it = 0; it < 4; ++it) {
    int s = it * 256 + tid;
    int row = s >> 3;
    int c16 = (s & 7) ^ (row & 7);
    soff[it] = s * 16;
    int p = m0 + row;
    int pp = (p < cntE) ? p : (cntE - 1);
    aptr[it] = abuf + (size_t)(base + pp) * I_DIM + c16 * 8;
    bptr[it] = wde + (size_t)row * I_DIM + c16 * 8;
  }

  f32x4v acc[4][4];
  #pragma unroll
  for (int m = 0; m < 4; ++m)
    #pragma unroll
    for (int n = 0; n < 4; ++n) acc[m][n] = f32x4v{0,0,0,0};

  int xk[2] = { g4 ^ (lane & 7), (4 + g4) ^ (lane & 7) };

  for (int kb = 0; kb < I_DIM; kb += 64) {
    #pragma unroll
    for (int it = 0; it < 4; ++it) {
      gld16(aptr[it] + kb, (char*)As + soff[it]);
      gld16(bptr[it] + kb, (char*)Bd + soff[it]);
    }
    __syncthreads();
    #pragma unroll
    for (int kk = 0; kk < 2; ++kk) {
      short8v a[4], b[4];
      int xo = xk[kk] * 16;
      #pragma unroll
      for (int m = 0; m < 4; ++m) {
        int row = wr + m * 16 + ln15;
        a[m] = *(const short8v*)((const char*)As + row * 128 + xo);
      }
      #pragma unroll
      for (int n = 0; n < 4; ++n) {
        int row = wc + n * 16 + ln15;
        b[n] = *(const short8v*)((const char*)Bd + row * 128 + xo);
      }
      #pragma unroll
      for (int m = 0; m < 4; ++m)
        #pragma unroll
        for (int n = 0; n < 4; ++n)
          acc[m][n] = __builtin_amdgcn_mfma_f32_16x16x32_bf16(a[m], b[n], acc[m][n], 0, 0, 0);
    }
    __syncthreads();
  }

  #pragma unroll
  for (int m = 0; m < 4; ++m) {
    #pragma unroll
    for (int r = 0; r < 4; ++r) {
      int row = wr + m * 16 + g4 * 4 + r;
      if (m0 + row < cntE) {
        float* orow = out + (size_t)tokloc[row] * H_DIM + n0 + wc;
        #pragma unroll
        for (int n = 0; n < 4; ++n)
          unsafeAtomicAdd(&orow[n * 16 + ln15], acc[m][n][r]);
      }
    }
  }
}

// ---------- launch ----------
extern "C" void kernel_launch(void* const* d_in, const int* in_sizes, int n_in,
                              void* d_out, int out_size, void* d_ws, size_t ws_size,
                              hipStream_t stream) {
  (void)in_sizes; (void)n_in;
  if (ws_size < WS_NEED) return;  // insufficient scratch; fail loudly (absmax) without corrupting

  const float* x  = (const float*)d_in[0];
  const float* rw = (const float*)d_in[1];
  const float* wg = (const float*)d_in[2];
  const float* wu = (const float*)d_in[3];
  const float* wd = (const float*)d_in[4];
  float* out = (float*)d_out;
  float* logits = out + (size_t)T_TOK * H_DIM;

  char* ws = (char*)d_ws;
  u16* xb   = (u16*)(ws + OFF_XB);
  u16* wgt  = (u16*)(ws + OFF_WGT);
  u16* wut  = (u16*)(ws + OFF_WUT);
  u16* wdt  = wgt;                      // alias: used only after gemm1 completes
  u16* abuf = (u16*)(ws + OFF_ABUF);
  int* sel   = (int*)(ws + OFF_SEL);
  float* wts = (float*)(ws + OFF_WTS);
  int* cnt   = (int*)(ws + OFF_CNT);
  int* offs  = (int*)(ws + OFF_OFFS);
  int* curs  = (int*)(ws + OFF_CURS);
  int* rtok  = (int*)(ws + OFF_RTOK);
  float* rwt = (float*)(ws + OFF_RWT);

  hipMemsetAsync(d_out, 0, (size_t)out_size * sizeof(float), stream);
  hipMemsetAsync(ws + OFF_CNT, 0, 128, stream);

  cvt_x_kernel<<<(T_TOK * H_DIM / 8) / 256, 256, 0, stream>>>(x, xb);
  tconv_kernel<<<dim3(I_DIM / 64, H_DIM / 64, E_NUM), 256, 0, stream>>>(wg, wgt, H_DIM, I_DIM);
  tconv_kernel<<<dim3(I_DIM / 64, H_DIM / 64, E_NUM), 256, 0, stream>>>(wu, wut, H_DIM, I_DIM);
  router_kernel<<<T_TOK / 4, 256, 0, stream>>>(x, rw, logits, sel, wts);
  hist_kernel<<<(T_TOK * TOPK) / 256, 256, 0, stream>>>(sel, cnt);
  prefix_kernel<<<1, 64, 0, stream>>>(cnt, offs, curs);
  scatter_kernel<<<(T_TOK * TOPK) / 256, 256, 0, stream>>>(sel, wts, curs, rtok, rwt);
  gemm1_kernel<<<dim3(I_DIM / 128, 16, E_NUM), 256, 0, stream>>>(xb, wgt, wut, cnt, offs, rtok, rwt, abuf);
  tconv_kernel<<<dim3(H_DIM / 64, I_DIM / 64, E_NUM), 256, 0, stream>>>(wd, wdt, I_DIM, H_DIM);
  gemm2_kernel<<<dim3(H_DIM / 128, 16, E_NUM), 256, 0, stream>>>(abuf, wdt, cnt, offs, rtok, out);
}

// Round 2
// 555.315 us; speedup vs baseline: 1.1316x; 1.1316x over previous
//
#include <hip/hip_runtime.h>
#include <hip/hip_bf16.h>

#define H_DIM 2048
#define T_TOK 2048
#define E_NUM 16
#define I_DIM 1024
#define TOPK  4

typedef short short8v __attribute__((ext_vector_type(8)));
typedef float f32x4v __attribute__((ext_vector_type(4)));
typedef unsigned short u16;
typedef unsigned int u32;

// ---------- ws layout (bytes) ----------
constexpr size_t OFF_XB   = 0;                                  // 8 MiB
constexpr size_t OFF_WGT  = OFF_XB   + (size_t)T_TOK*H_DIM*2;   // 64 MiB (aliased by wd_t later)
constexpr size_t OFF_WUT  = OFF_WGT  + (size_t)E_NUM*H_DIM*I_DIM*2; // 64 MiB (aliased by pbuf later)
constexpr size_t OFF_ABUF = OFF_WUT  + (size_t)E_NUM*H_DIM*I_DIM*2; // 16 MiB
constexpr size_t OFF_SEL  = OFF_ABUF + (size_t)T_TOK*TOPK*I_DIM*2;
constexpr size_t OFF_WTS  = OFF_SEL  + (size_t)T_TOK*TOPK*4;
constexpr size_t OFF_CNT  = OFF_WTS  + (size_t)T_TOK*TOPK*4;
constexpr size_t OFF_OFFS = OFF_CNT  + 128;
constexpr size_t OFF_CURS = OFF_OFFS + 128;
constexpr size_t OFF_RTOK = OFF_CURS + 128;
constexpr size_t OFF_RWT  = OFF_RTOK + (size_t)T_TOK*TOPK*4;
constexpr size_t OFF_PPOS = OFF_RWT  + (size_t)T_TOK*TOPK*4;
constexpr size_t WS_NEED  = OFF_PPOS + (size_t)T_TOK*TOPK*4;

// ---------- helpers ----------
__device__ __forceinline__ u16 f2b(float f) {   // fp32 -> bf16 RNE
  u32 u = __builtin_bit_cast(u32, f);
  u32 r = (u + 0x7FFFu + ((u >> 16) & 1u)) >> 16;
  return (u16)r;
}

__device__ __forceinline__ void gld16(const void* g, void* l) {
  __builtin_amdgcn_global_load_lds(
      (const __attribute__((address_space(1))) u32*)g,
      (__attribute__((address_space(3))) u32*)l, 16, 0, 0);
}

// ---------- fp32 -> bf16 (x) ----------
__global__ __launch_bounds__(256) void cvt_x_kernel(const float* __restrict__ src,
                                                    u16* __restrict__ dst) {
  int i = blockIdx.x * 256 + threadIdx.x;
  const float4* s = (const float4*)src + (size_t)i * 2;
  float4 a = s[0], b = s[1];
  uint4 o;
  o.x = (u32)f2b(a.x) | ((u32)f2b(a.y) << 16);
  o.y = (u32)f2b(a.z) | ((u32)f2b(a.w) << 16);
  o.z = (u32)f2b(b.x) | ((u32)f2b(b.y) << 16);
  o.w = (u32)f2b(b.z) | ((u32)f2b(b.w) << 16);
  ((uint4*)dst)[i] = o;
}

// ---------- fp32 (R,C) -> bf16 (C,R) transpose-convert, per expert ----------
__global__ __launch_bounds__(256) void tconv_kernel(const float* __restrict__ src,
                                                    u16* __restrict__ dst,
                                                    int R, int C) {
  __shared__ u16 lds[64 * 68];
  int e = blockIdx.z;
  int rb = blockIdx.y * 64, cb = blockIdx.x * 64;
  const float* se = src + (size_t)e * R * C;
  u16* de = dst + (size_t)e * R * C;
  #pragma unroll
  for (int it = 0; it < 16; ++it) {
    int idx = it * 256 + threadIdx.x;
    int r = idx >> 6, c = idx & 63;
    float v = se[(size_t)(rb + r) * C + cb + c];
    lds[c * 68 + r] = f2b(v);
  }
  __syncthreads();
  #pragma unroll
  for (int it = 0; it < 4; ++it) {
    int v = it * 256 + threadIdx.x;
    int c = v >> 4, r4 = (v & 15) * 4;
    uint2 val = *(const uint2*)&lds[c * 68 + r4];
    *(uint2*)&de[(size_t)(cb + c) * R + rb + r4] = val;
  }
}

// ---------- router ----------
__global__ __launch_bounds__(256) void router_kernel(const float* __restrict__ x,
                                                     const float* __restrict__ rw,
                                                     float* __restrict__ logits,
                                                     int* __restrict__ sel,
                                                     float* __restrict__ wts) {
  int w = threadIdx.x >> 6, lane = threadIdx.x & 63;
  int t = blockIdx.x * 4 + w;
  const float* xt = x + (size_t)t * H_DIM;
  float le[E_NUM];
  float mine = 0.f;
  #pragma unroll
  for (int e = 0; e < E_NUM; ++e) {
    const float* we = rw + (size_t)e * H_DIM;
    float s = 0.f;
    for (int h = lane; h < H_DIM; h += 64) s += xt[h] * we[h];
    #pragma unroll
    for (int off = 32; off; off >>= 1) s += __shfl_xor(s, off);
    le[e] = s;
    if (lane == e) mine = s;
  }
  if (lane < E_NUM) logits[(size_t)t * E_NUM + lane] = mine;
  int taken = 0;
  float tv[TOPK]; int ti[TOPK];
  #pragma unroll
  for (int k = 0; k < TOPK; ++k) {
    float bv = -1e30f; int bi = 0;
    #pragma unroll
    for (int e = 0; e < E_NUM; ++e) {
      bool ok = !(taken & (1 << e));
      if (ok && le[e] > bv) { bv = le[e]; bi = e; }
    }
    taken |= (1 << bi); tv[k] = bv; ti[k] = bi;
  }
  float m = tv[0];
  float ew[TOPK]; float ssum = 0.f;
  #pragma unroll
  for (int k = 0; k < TOPK; ++k) { ew[k] = __expf(tv[k] - m); ssum += ew[k]; }
  if (lane == 0) {
    float inv = 1.f / ssum;
    #pragma unroll
    for (int k = 0; k < TOPK; ++k) {
      sel[t * TOPK + k] = ti[k];
      wts[t * TOPK + k] = ew[k] * inv;
    }
  }
}

// ---------- grouping ----------
__global__ void hist_kernel(const int* __restrict__ sel, int* __restrict__ cnt) {
  int p = blockIdx.x * 256 + threadIdx.x;
  if (p < T_TOK * TOPK) atomicAdd(&cnt[sel[p]], 1);
}

__global__ void prefix_kernel(const int* __restrict__ cnt, int* __restrict__ offs,
                              int* __restrict__ curs) {
  if (threadIdx.x == 0) {
    int a = 0;
    for (int e = 0; e < E_NUM; ++e) { offs[e] = a; curs[e] = a; a += cnt[e]; }
    offs[E_NUM] = a;
  }
}

__global__ void scatter_kernel(const int* __restrict__ sel, const float* __restrict__ wts,
                               int* __restrict__ curs, int* __restrict__ rtok,
                               float* __restrict__ rwt, int* __restrict__ ppos) {
  int p = blockIdx.x * 256 + threadIdx.x;
  if (p >= T_TOK * TOPK) return;
  int e = sel[p];
  int pos = atomicAdd(&curs[e], 1);
  rtok[pos] = p >> 2;
  rwt[pos] = wts[p];
  ppos[p] = pos;
}

// ---------- GEMM1: x @ [gate^T ; up^T] -> silu(g)*u*wt -> abuf (bf16) ----------
// 128M x 64N tile; B tile = 128 LDS rows: rows 0-63 gate cols, 64-127 up cols.
// One A + one B stream -> 32KB LDS (4 blocks/CU), ~1100 working blocks.
// Same thread holds g (acc[m][0..1]) and u (acc[m][2..3]) for one output col.
__global__ __launch_bounds__(256) void gemm1_kernel(
    const u16* __restrict__ xb, const u16* __restrict__ wg, const u16* __restrict__ wu,
    const int* __restrict__ cnt, const int* __restrict__ offs,
    const int* __restrict__ rtok, const float* __restrict__ rwt,
    u16* __restrict__ abuf) {
  int e = blockIdx.z;
  int cntE = cnt[e];
  int m0 = blockIdx.y * 128;
  if (m0 >= cntE) return;
  int n0 = blockIdx.x * 64;
  int base = offs[e];

  __shared__ alignas(16) u16 As[128 * 64];
  __shared__ alignas(16) u16 Bs[128 * 64];
  __shared__ int tokloc[128];
  __shared__ float wtloc[128];

  int tid = threadIdx.x;
  for (int i = tid; i < 128; i += 256) {
    int p = m0 + i;
    int pp = (p < cntE) ? p : (cntE - 1);
    tokloc[i] = rtok[base + pp];
    wtloc[i] = (p < cntE) ? rwt[base + pp] : 0.f;
  }
  __syncthreads();

  int lane = tid & 63;
  int w = tid >> 6;
  int wr = (w >> 1) * 64, wc = (w & 1) * 32;
  int ln15 = lane & 15, g4 = lane >> 4;

  const u16* wge = wg + ((size_t)e * I_DIM + n0) * H_DIM;
  const u16* wue = wu + ((size_t)e * I_DIM + n0) * H_DIM;

  const u16* aptr[4]; const u16* bptr[4]; int soff[4];
  #pragma unroll
  for (int it = 0; it < 4; ++it) {
    int s = it * 256 + tid;
    int row = s >> 3;
    int c16 = (s & 7) ^ (row & 7);
    soff[it] = s * 16;
    aptr[it] = xb + (size_t)tokloc[row] * H_DIM + c16 * 8;
    bptr[it] = (row < 64 ? wge + (size_t)row * H_DIM
                         : wue + (size_t)(row - 64) * H_DIM) + c16 * 8;
  }

  f32x4v acc[4][4];
  #pragma unroll
  for (int m = 0; m < 4; ++m)
    #pragma unroll
    for (int n = 0; n < 4; ++n) acc[m][n] = f32x4v{0,0,0,0};

  int xk[2] = { g4 ^ (lane & 7), (4 + g4) ^ (lane & 7) };

  for (int kb = 0; kb < H_DIM; kb += 64) {
    #pragma unroll
    for (int it = 0; it < 4; ++it) {
      gld16(aptr[it] + kb, (char*)As + soff[it]);
      gld16(bptr[it] + kb, (char*)Bs + soff[it]);
    }
    __syncthreads();
    #pragma unroll
    for (int kk = 0; kk < 2; ++kk) {
      short8v a[4], b[4];
      int xo = xk[kk] * 16;
      #pragma unroll
      for (int m = 0; m < 4; ++m) {
        int row = wr + m * 16 + ln15;
        a[m] = *(const short8v*)((const char*)As + row * 128 + xo);
      }
      #pragma unroll
      for (int n = 0; n < 4; ++n) {
        int brow = (n < 2) ? (wc + n * 16 + ln15) : (64 + wc + (n - 2) * 16 + ln15);
        b[n] = *(const short8v*)((const char*)Bs + brow * 128 + xo);
      }
      #pragma unroll
      for (int m = 0; m < 4; ++m)
        #pragma unroll
        for (int n = 0; n < 4; ++n)
          acc[m][n] = __builtin_amdgcn_mfma_f32_16x16x32_bf16(a[m], b[n], acc[m][n], 0, 0, 0);
    }
    __syncthreads();
  }

  #pragma unroll
  for (int m = 0; m < 4; ++m) {
    #pragma unroll
    for (int r = 0; r < 4; ++r) {
      int row = wr + m * 16 + g4 * 4 + r;
      if (m0 + row < cntE) {
        float wt = wtloc[row];
        size_t orow = (size_t)(base + m0 + row) * I_DIM + n0 + wc;
        #pragma unroll
        for (int j = 0; j < 2; ++j) {
          float g = acc[m][j][r], u = acc[m][j + 2][r];
          float aa = g / (1.f + __expf(-g)) * u * wt;
          abuf[orow + j * 16 + ln15] = f2b(aa);
        }
      }
    }
  }
}

// ---------- GEMM2: abuf @ w_down^T -> pbuf (f32, grouped-position rows) ----------
__global__ __launch_bounds__(256) void gemm2_kernel(
    const u16* __restrict__ abuf, const u16* __restrict__ wd,
    const int* __restrict__ cnt, const int* __restrict__ offs,
    float* __restrict__ pbuf) {
  int e = blockIdx.z;
  int cntE = cnt[e];
  int m0 = blockIdx.y * 128;
  if (m0 >= cntE) return;
  int n0 = blockIdx.x * 128;
  int base = offs[e];

  __shared__ alignas(16) u16 As[128 * 64];
  __shared__ alignas(16) u16 Bd[128 * 64];

  int tid = threadIdx.x;
  int lane = tid & 63;
  int w = tid >> 6;
  int wr = (w >> 1) * 64, wc = (w & 1) * 64;
  int ln15 = lane & 15, g4 = lane >> 4;

  const u16* wde = wd + ((size_t)e * H_DIM + n0) * I_DIM;

  const u16* aptr[4]; const u16* bptr[4]; int soff[4];
  #pragma unroll
  for (int it = 0; it < 4; ++it) {
    int s = it * 256 + tid;
    int row = s >> 3;
    int c16 = (s & 7) ^ (row & 7);
    soff[it] = s * 16;
    int p = m0 + row;
    int pp = (p < cntE) ? p : (cntE - 1);
    aptr[it] = abuf + (size_t)(base + pp) * I_DIM + c16 * 8;
    bptr[it] = wde + (size_t)row * I_DIM + c16 * 8;
  }

  f32x4v acc[4][4];
  #pragma unroll
  for (int m = 0; m < 4; ++m)
    #pragma unroll
    for (int n = 0; n < 4; ++n) acc[m][n] = f32x4v{0,0,0,0};

  int xk[2] = { g4 ^ (lane & 7), (4 + g4) ^ (lane & 7) };

  for (int kb = 0; kb < I_DIM; kb += 64) {
    #pragma unroll
    for (int it = 0; it < 4; ++it) {
      gld16(aptr[it] + kb, (char*)As + soff[it]);
      gld16(bptr[it] + kb, (char*)Bd + soff[it]);
    }
    __syncthreads();
    #pragma unroll
    for (int kk = 0; kk < 2; ++kk) {
      short8v a[4], b[4];
      int xo = xk[kk] * 16;
      #pragma unroll
      for (int m = 0; m < 4; ++m) {
        int row = wr + m * 16 + ln15;
        a[m] = *(const short8v*)((const char*)As + row * 128 + xo);
      }
      #pragma unroll
      for (int n = 0; n < 4; ++n) {
        int row = wc + n * 16 + ln15;
        b[n] = *(const short8v*)((const char*)Bd + row * 128 + xo);
      }
      #pragma unroll
      for (int m = 0; m < 4; ++m)
        #pragma unroll
        for (int n = 0; n < 4; ++n)
          acc[m][n] = __builtin_amdgcn_mfma_f32_16x16x32_bf16(a[m], b[n], acc[m][n], 0, 0, 0);
    }
    __syncthreads();
  }

  #pragma unroll
  for (int m = 0; m < 4; ++m) {
    #pragma unroll
    for (int r = 0; r < 4; ++r) {
      int row = wr + m * 16 + g4 * 4 + r;
      if (m0 + row < cntE) {
        float* orow = pbuf + (size_t)(base + m0 + row) * H_DIM + n0 + wc;
        #pragma unroll
        for (int n = 0; n < 4; ++n)
          orow[n * 16 + ln15] = acc[m][n][r];
      }
    }
  }
}

// ---------- combine: out[t] = sum_k pbuf[ppos[t][k]] ----------
__global__ __launch_bounds__(256) void combine_kernel(const float* __restrict__ pbuf,
                                                      const int* __restrict__ ppos,
                                                      float* __restrict__ out) {
  int idx = blockIdx.x * 256 + threadIdx.x;     // over T * (H/4)
  int t = idx >> 9;
  int h4 = (idx & 511) * 4;
  int4 pp = ((const int4*)ppos)[t];
  float4 s0 = *(const float4*)&pbuf[(size_t)pp.x * H_DIM + h4];
  float4 s1 = *(const float4*)&pbuf[(size_t)pp.y * H_DIM + h4];
  float4 s2 = *(const float4*)&pbuf[(size_t)pp.z * H_DIM + h4];
  float4 s3 = *(const float4*)&pbuf[(size_t)pp.w * H_DIM + h4];
  float4 o;
  o.x = s0.x + s1.x + s2.x + s3.x;
  o.y = s0.y + s1.y + s2.y + s3.y;
  o.z = s0.z + s1.z + s2.z + s3.z;
  o.w = s0.w + s1.w + s2.w + s3.w;
  *(float4*)&out[(size_t)t * H_DIM + h4] = o;
}

// ---------- launch ----------
extern "C" void kernel_launch(void* const* d_in, const int* in_sizes, int n_in,
                              void* d_out, int out_size, void* d_ws, size_t ws_size,
                              hipStream_t stream) {
  (void)in_sizes; (void)n_in; (void)out_size;
  if (ws_size < WS_NEED) return;

  const float* x  = (const float*)d_in[0];
  const float* rw = (const float*)d_in[1];
  const float* wg = (const float*)d_in[2];
  const float* wu = (const float*)d_in[3];
  const float* wd = (const float*)d_in[4];
  float* out = (float*)d_out;
  float* logits = out + (size_t)T_TOK * H_DIM;

  char* ws = (char*)d_ws;
  u16* xb   = (u16*)(ws + OFF_XB);
  u16* wgt  = (u16*)(ws + OFF_WGT);
  u16* wut  = (u16*)(ws + OFF_WUT);
  u16* wdt  = wgt;                       // alias: used only after gemm1
  float* pbuf = (float*)(ws + OFF_WUT);  // alias: used only after gemm1
  u16* abuf = (u16*)(ws + OFF_ABUF);
  int* sel   = (int*)(ws + OFF_SEL);
  float* wts = (float*)(ws + OFF_WTS);
  int* cnt   = (int*)(ws + OFF_CNT);
  int* offs  = (int*)(ws + OFF_OFFS);
  int* curs  = (int*)(ws + OFF_CURS);
  int* rtok  = (int*)(ws + OFF_RTOK);
  float* rwt = (float*)(ws + OFF_RWT);
  int* ppos  = (int*)(ws + OFF_PPOS);

  hipMemsetAsync(ws + OFF_CNT, 0, 128, stream);

  cvt_x_kernel<<<(T_TOK * H_DIM / 8) / 256, 256, 0, stream>>>(x, xb);
  tconv_kernel<<<dim3(I_DIM / 64, H_DIM / 64, E_NUM), 256, 0, stream>>>(wg, wgt, H_DIM, I_DIM);
  tconv_kernel<<<dim3(I_DIM / 64, H_DIM / 64, E_NUM), 256, 0, stream>>>(wu, wut, H_DIM, I_DIM);
  router_kernel<<<T_TOK / 4, 256, 0, stream>>>(x, rw, logits, sel, wts);
  hist_kernel<<<(T_TOK * TOPK) / 256, 256, 0, stream>>>(sel, cnt);
  prefix_kernel<<<1, 64, 0, stream>>>(cnt, offs, curs);
  scatter_kernel<<<(T_TOK * TOPK) / 256, 256, 0, stream>>>(sel, wts, curs, rtok, rwt, ppos);
  gemm1_kernel<<<dim3(I_DIM / 64, 16, E_NUM), 256, 0, stream>>>(xb, wgt, wut, cnt, offs, rtok, rwt, abuf);
  tconv_kernel<<<dim3(H_DIM / 64, I_DIM / 64, E_NUM), 256, 0, stream>>>(wd, wdt, I_DIM, H_DIM);
  gemm2_kernel<<<dim3(H_DIM / 128, 16, E_NUM), 256, 0, stream>>>(abuf, wdt, cnt, offs, pbuf);
  combine_kernel<<<(T_TOK * (H_DIM / 4)) / 256, 256, 0, stream>>>(pbuf, ppos, out);
}

// Round 3
// 392.157 us; speedup vs baseline: 1.6024x; 1.4161x over previous
//
#include <hip/hip_runtime.h>
#include <hip/hip_bf16.h>

#define H_DIM 2048
#define T_TOK 2048
#define E_NUM 16
#define I_DIM 1024
#define TOPK  4

typedef short short8v __attribute__((ext_vector_type(8)));
typedef float f32x4v __attribute__((ext_vector_type(4)));
typedef unsigned short u16;
typedef unsigned int u32;

// ---------- ws layout (bytes) ----------
constexpr size_t OFF_XB   = 0;                                  // 8 MiB
constexpr size_t OFF_WGT  = OFF_XB   + (size_t)T_TOK*H_DIM*2;   // 64 MiB (aliased by wd_t later)
constexpr size_t OFF_WUT  = OFF_WGT  + (size_t)E_NUM*H_DIM*I_DIM*2; // 64 MiB (aliased by pbuf later)
constexpr size_t OFF_ABUF = OFF_WUT  + (size_t)E_NUM*H_DIM*I_DIM*2; // 16 MiB
constexpr size_t OFF_SEL  = OFF_ABUF + (size_t)T_TOK*TOPK*I_DIM*2;
constexpr size_t OFF_WTS  = OFF_SEL  + (size_t)T_TOK*TOPK*4;
constexpr size_t OFF_CNT  = OFF_WTS  + (size_t)T_TOK*TOPK*4;
constexpr size_t OFF_OFFS = OFF_CNT  + 128;
constexpr size_t OFF_CURS = OFF_OFFS + 128;
constexpr size_t OFF_RTOK = OFF_CURS + 128;
constexpr size_t OFF_RWT  = OFF_RTOK + (size_t)T_TOK*TOPK*4;
constexpr size_t OFF_PPOS = OFF_RWT  + (size_t)T_TOK*TOPK*4;
constexpr size_t WS_NEED  = OFF_PPOS + (size_t)T_TOK*TOPK*4;

// ---------- helpers ----------
__device__ __forceinline__ u16 f2b(float f) {   // fp32 -> bf16 RNE
  u32 u = __builtin_bit_cast(u32, f);
  u32 r = (u + 0x7FFFu + ((u >> 16) & 1u)) >> 16;
  return (u16)r;
}

__device__ __forceinline__ void gld16(const void* g, void* l) {
  __builtin_amdgcn_global_load_lds(
      (const __attribute__((address_space(1))) u32*)g,
      (__attribute__((address_space(3))) u32*)l, 16, 0, 0);
}

// ---------- fp32 -> bf16 (x) ----------
__global__ __launch_bounds__(256) void cvt_x_kernel(const float* __restrict__ src,
                                                    u16* __restrict__ dst) {
  int i = blockIdx.x * 256 + threadIdx.x;
  const float4* s = (const float4*)src + (size_t)i * 2;
  float4 a = s[0], b = s[1];
  uint4 o;
  o.x = (u32)f2b(a.x) | ((u32)f2b(a.y) << 16);
  o.y = (u32)f2b(a.z) | ((u32)f2b(a.w) << 16);
  o.z = (u32)f2b(b.x) | ((u32)f2b(b.y) << 16);
  o.w = (u32)f2b(b.z) | ((u32)f2b(b.w) << 16);
  ((uint4*)dst)[i] = o;
}

// ---------- fp32 (R,C) -> bf16 (C,R) transpose-convert, per expert ----------
__global__ __launch_bounds__(256) void tconv_kernel(const float* __restrict__ src,
                                                    u16* __restrict__ dst,
                                                    int R, int C) {
  __shared__ u16 lds[64 * 68];
  int e = blockIdx.z;
  int rb = blockIdx.y * 64, cb = blockIdx.x * 64;
  const float* se = src + (size_t)e * R * C;
  u16* de = dst + (size_t)e * R * C;
  #pragma unroll
  for (int it = 0; it < 16; ++it) {
    int idx = it * 256 + threadIdx.x;
    int r = idx >> 6, c = idx & 63;
    float v = se[(size_t)(rb + r) * C + cb + c];
    lds[c * 68 + r] = f2b(v);
  }
  __syncthreads();
  #pragma unroll
  for (int it = 0; it < 4; ++it) {
    int v = it * 256 + threadIdx.x;
    int c = v >> 4, r4 = (v & 15) * 4;
    uint2 val = *(const uint2*)&lds[c * 68 + r4];
    *(uint2*)&de[(size_t)(cb + c) * R + rb + r4] = val;
  }
}

// ---------- router: vectorized fp32 logits, top-4, softmax ----------
// One wave per token. Lane holds 32 x-floats (8 x float4) in registers,
// streams all 16 expert rows (L1/L2-resident) against them, shuffle-reduce.
__global__ __launch_bounds__(256) void router_kernel(const float* __restrict__ x,
                                                     const float* __restrict__ rw,
                                                     float* __restrict__ logits,
                                                     int* __restrict__ sel,
                                                     float* __restrict__ wts) {
  int w = threadIdx.x >> 6, lane = threadIdx.x & 63;
  int t = blockIdx.x * 4 + w;

  const float4* xt = (const float4*)(x + (size_t)t * H_DIM);
  float4 xv[8];
  #pragma unroll
  for (int j = 0; j < 8; ++j) xv[j] = xt[j * 64 + lane];

  const float4* rw4 = (const float4*)rw;
  float le[E_NUM];
  #pragma unroll
  for (int e = 0; e < E_NUM; ++e) {
    float s = 0.f;
    #pragma unroll
    for (int j = 0; j < 8; ++j) {
      float4 wv = rw4[e * (H_DIM / 4) + j * 64 + lane];
      s += xv[j].x * wv.x + xv[j].y * wv.y + xv[j].z * wv.z + xv[j].w * wv.w;
    }
    #pragma unroll
    for (int off = 32; off; off >>= 1) s += __shfl_xor(s, off);
    le[e] = s;   // all lanes hold logit e (static index)
  }

  // top-4, strict > so ties pick lower index (matches jax.lax.top_k)
  int taken = 0;
  float tv[TOPK]; int ti[TOPK];
  #pragma unroll
  for (int k = 0; k < TOPK; ++k) {
    float bv = -1e30f; int bi = 0;
    #pragma unroll
    for (int e = 0; e < E_NUM; ++e) {
      bool ok = !(taken & (1 << e));
      if (ok && le[e] > bv) { bv = le[e]; bi = e; }
    }
    taken |= (1 << bi); tv[k] = bv; ti[k] = bi;
  }
  float m = tv[0];
  float ew[TOPK]; float ssum = 0.f;
  #pragma unroll
  for (int k = 0; k < TOPK; ++k) { ew[k] = __expf(tv[k] - m); ssum += ew[k]; }
  if (lane == 0) {
    #pragma unroll
    for (int e = 0; e < E_NUM; ++e) logits[(size_t)t * E_NUM + e] = le[e];
    float inv = 1.f / ssum;
    #pragma unroll
    for (int k = 0; k < TOPK; ++k) {
      sel[t * TOPK + k] = ti[k];
      wts[t * TOPK + k] = ew[k] * inv;
    }
  }
}

// ---------- grouping ----------
__global__ void hist_kernel(const int* __restrict__ sel, int* __restrict__ cnt) {
  int p = blockIdx.x * 256 + threadIdx.x;
  if (p < T_TOK * TOPK) atomicAdd(&cnt[sel[p]], 1);
}

__global__ void prefix_kernel(const int* __restrict__ cnt, int* __restrict__ offs,
                              int* __restrict__ curs) {
  if (threadIdx.x == 0) {
    int a = 0;
    for (int e = 0; e < E_NUM; ++e) { offs[e] = a; curs[e] = a; a += cnt[e]; }
    offs[E_NUM] = a;
  }
}

__global__ void scatter_kernel(const int* __restrict__ sel, const float* __restrict__ wts,
                               int* __restrict__ curs, int* __restrict__ rtok,
                               float* __restrict__ rwt, int* __restrict__ ppos) {
  int p = blockIdx.x * 256 + threadIdx.x;
  if (p >= T_TOK * TOPK) return;
  int e = sel[p];
  int pos = atomicAdd(&curs[e], 1);
  rtok[pos] = p >> 2;
  rwt[pos] = wts[p];
  ppos[p] = pos;
}

// ---------- GEMM1: x @ [gate^T ; up^T] -> silu(g)*u*wt -> abuf (bf16) ----------
__global__ __launch_bounds__(256) void gemm1_kernel(
    const u16* __restrict__ xb, const u16* __restrict__ wg, const u16* __restrict__ wu,
    const int* __restrict__ cnt, const int* __restrict__ offs,
    const int* __restrict__ rtok, const float* __restrict__ rwt,
    u16* __restrict__ abuf) {
  int e = blockIdx.z;
  int cntE = cnt[e];
  int m0 = blockIdx.y * 128;
  if (m0 >= cntE) return;
  int n0 = blockIdx.x * 64;
  int base = offs[e];

  __shared__ alignas(16) u16 As[128 * 64];
  __shared__ alignas(16) u16 Bs[128 * 64];
  __shared__ int tokloc[128];
  __shared__ float wtloc[128];

  int tid = threadIdx.x;
  for (int i = tid; i < 128; i += 256) {
    int p = m0 + i;
    int pp = (p < cntE) ? p : (cntE - 1);
    tokloc[i] = rtok[base + pp];
    wtloc[i] = (p < cntE) ? rwt[base + pp] : 0.f;
  }
  __syncthreads();

  int lane = tid & 63;
  int w = tid >> 6;
  int wr = (w >> 1) * 64, wc = (w & 1) * 32;
  int ln15 = lane & 15, g4 = lane >> 4;

  const u16* wge = wg + ((size_t)e * I_DIM + n0) * H_DIM;
  const u16* wue = wu + ((size_t)e * I_DIM + n0) * H_DIM;

  const u16* aptr[4]; const u16* bptr[4]; int soff[4];
  #pragma unroll
  for (int it = 0; it < 4; ++it) {
    int s = it * 256 + tid;
    int row = s >> 3;
    int c16 = (s & 7) ^ (row & 7);
    soff[it] = s * 16;
    aptr[it] = xb + (size_t)tokloc[row] * H_DIM + c16 * 8;
    bptr[it] = (row < 64 ? wge + (size_t)row * H_DIM
                         : wue + (size_t)(row - 64) * H_DIM) + c16 * 8;
  }

  f32x4v acc[4][4];
  #pragma unroll
  for (int m = 0; m < 4; ++m)
    #pragma unroll
    for (int n = 0; n < 4; ++n) acc[m][n] = f32x4v{0,0,0,0};

  int xk[2] = { g4 ^ (lane & 7), (4 + g4) ^ (lane & 7) };

  for (int kb = 0; kb < H_DIM; kb += 64) {
    #pragma unroll
    for (int it = 0; it < 4; ++it) {
      gld16(aptr[it] + kb, (char*)As + soff[it]);
      gld16(bptr[it] + kb, (char*)Bs + soff[it]);
    }
    __syncthreads();
    #pragma unroll
    for (int kk = 0; kk < 2; ++kk) {
      short8v a[4], b[4];
      int xo = xk[kk] * 16;
      #pragma unroll
      for (int m = 0; m < 4; ++m) {
        int row = wr + m * 16 + ln15;
        a[m] = *(const short8v*)((const char*)As + row * 128 + xo);
      }
      #pragma unroll
      for (int n = 0; n < 4; ++n) {
        int brow = (n < 2) ? (wc + n * 16 + ln15) : (64 + wc + (n - 2) * 16 + ln15);
        b[n] = *(const short8v*)((const char*)Bs + brow * 128 + xo);
      }
      #pragma unroll
      for (int m = 0; m < 4; ++m)
        #pragma unroll
        for (int n = 0; n < 4; ++n)
          acc[m][n] = __builtin_amdgcn_mfma_f32_16x16x32_bf16(a[m], b[n], acc[m][n], 0, 0, 0);
    }
    __syncthreads();
  }

  #pragma unroll
  for (int m = 0; m < 4; ++m) {
    #pragma unroll
    for (int r = 0; r < 4; ++r) {
      int row = wr + m * 16 + g4 * 4 + r;
      if (m0 + row < cntE) {
        float wt = wtloc[row];
        size_t orow = (size_t)(base + m0 + row) * I_DIM + n0 + wc;
        #pragma unroll
        for (int j = 0; j < 2; ++j) {
          float g = acc[m][j][r], u = acc[m][j + 2][r];
          float aa = g / (1.f + __expf(-g)) * u * wt;
          abuf[orow + j * 16 + ln15] = f2b(aa);
        }
      }
    }
  }
}

// ---------- GEMM2: abuf @ w_down^T -> pbuf (f32, grouped-position rows) ----------
__global__ __launch_bounds__(256) void gemm2_kernel(
    const u16* __restrict__ abuf, const u16* __restrict__ wd,
    const int* __restrict__ cnt, const int* __restrict__ offs,
    float* __restrict__ pbuf) {
  int e = blockIdx.z;
  int cntE = cnt[e];
  int m0 = blockIdx.y * 128;
  if (m0 >= cntE) return;
  int n0 = blockIdx.x * 128;
  int base = offs[e];

  __shared__ alignas(16) u16 As[128 * 64];
  __shared__ alignas(16) u16 Bd[128 * 64];

  int tid = threadIdx.x;
  int lane = tid & 63;
  int w = tid >> 6;
  int wr = (w >> 1) * 64, wc = (w & 1) * 64;
  int ln15 = lane & 15, g4 = lane >> 4;

  const u16* wde = wd + ((size_t)e * H_DIM + n0) * I_DIM;

  const u16* aptr[4]; const u16* bptr[4]; int soff[4];
  #pragma unroll
  for (int it = 0; it < 4; ++it) {
    int s = it * 256 + tid;
    int row = s >> 3;
    int c16 = (s & 7) ^ (row & 7);
    soff[it] = s * 16;
    int p = m0 + row;
    int pp = (p < cntE) ? p : (cntE - 1);
    aptr[it] = abuf + (size_t)(base + pp) * I_DIM + c16 * 8;
    bptr[it] = wde + (size_t)row * I_DIM + c16 * 8;
  }

  f32x4v acc[4][4];
  #pragma unroll
  for (int m = 0; m < 4; ++m)
    #pragma unroll
    for (int n = 0; n < 4; ++n) acc[m][n] = f32x4v{0,0,0,0};

  int xk[2] = { g4 ^ (lane & 7), (4 + g4) ^ (lane & 7) };

  for (int kb = 0; kb < I_DIM; kb += 64) {
    #pragma unroll
    for (int it = 0; it < 4; ++it) {
      gld16(aptr[it] + kb, (char*)As + soff[it]);
      gld16(bptr[it] + kb, (char*)Bd + soff[it]);
    }
    __syncthreads();
    #pragma unroll
    for (int kk = 0; kk < 2; ++kk) {
      short8v a[4], b[4];
      int xo = xk[kk] * 16;
      #pragma unroll
      for (int m = 0; m < 4; ++m) {
        int row = wr + m * 16 + ln15;
        a[m] = *(const short8v*)((const char*)As + row * 128 + xo);
      }
      #pragma unroll
      for (int n = 0; n < 4; ++n) {
        int row = wc + n * 16 + ln15;
        b[n] = *(const short8v*)((const char*)Bd + row * 128 + xo);
      }
      #pragma unroll
      for (int m = 0; m < 4; ++m)
        #pragma unroll
        for (int n = 0; n < 4; ++n)
          acc[m][n] = __builtin_amdgcn_mfma_f32_16x16x32_bf16(a[m], b[n], acc[m][n], 0, 0, 0);
    }
    __syncthreads();
  }

  #pragma unroll
  for (int m = 0; m < 4; ++m) {
    #pragma unroll
    for (int r = 0; r < 4; ++r) {
      int row = wr + m * 16 + g4 * 4 + r;
      if (m0 + row < cntE) {
        float* orow = pbuf + (size_t)(base + m0 + row) * H_DIM + n0 + wc;
        #pragma unroll
        for (int n = 0; n < 4; ++n)
          orow[n * 16 + ln15] = acc[m][n][r];
      }
    }
  }
}

// ---------- combine: out[t] = sum_k pbuf[ppos[t][k]] ----------
__global__ __launch_bounds__(256) void combine_kernel(const float* __restrict__ pbuf,
                                                      const int* __restrict__ ppos,
                                                      float* __restrict__ out) {
  int idx = blockIdx.x * 256 + threadIdx.x;     // over T * (H/4)
  int t = idx >> 9;
  int h4 = (idx & 511) * 4;
  int4 pp = ((const int4*)ppos)[t];
  float4 s0 = *(const float4*)&pbuf[(size_t)pp.x * H_DIM + h4];
  float4 s1 = *(const float4*)&pbuf[(size_t)pp.y * H_DIM + h4];
  float4 s2 = *(const float4*)&pbuf[(size_t)pp.z * H_DIM + h4];
  float4 s3 = *(const float4*)&pbuf[(size_t)pp.w * H_DIM + h4];
  float4 o;
  o.x = s0.x + s1.x + s2.x + s3.x;
  o.y = s0.y + s1.y + s2.y + s3.y;
  o.z = s0.z + s1.z + s2.z + s3.z;
  o.w = s0.w + s1.w + s2.w + s3.w;
  *(float4*)&out[(size_t)t * H_DIM + h4] = o;
}

// ---------- launch ----------
extern "C" void kernel_launch(void* const* d_in, const int* in_sizes, int n_in,
                              void* d_out, int out_size, void* d_ws, size_t ws_size,
                              hipStream_t stream) {
  (void)in_sizes; (void)n_in; (void)out_size;
  if (ws_size < WS_NEED) return;

  const float* x  = (const float*)d_in[0];
  const float* rw = (const float*)d_in[1];
  const float* wg = (const float*)d_in[2];
  const float* wu = (const float*)d_in[3];
  const float* wd = (const float*)d_in[4];
  float* out = (float*)d_out;
  float* logits = out + (size_t)T_TOK * H_DIM;

  char* ws = (char*)d_ws;
  u16* xb   = (u16*)(ws + OFF_XB);
  u16* wgt  = (u16*)(ws + OFF_WGT);
  u16* wut  = (u16*)(ws + OFF_WUT);
  u16* wdt  = wgt;                       // alias: used only after gemm1
  float* pbuf = (float*)(ws + OFF_WUT);  // alias: used only after gemm1
  u16* abuf = (u16*)(ws + OFF_ABUF);
  int* sel   = (int*)(ws + OFF_SEL);
  float* wts = (float*)(ws + OFF_WTS);
  int* cnt   = (int*)(ws + OFF_CNT);
  int* offs  = (int*)(ws + OFF_OFFS);
  int* curs  = (int*)(ws + OFF_CURS);
  int* rtok  = (int*)(ws + OFF_RTOK);
  float* rwt = (float*)(ws + OFF_RWT);
  int* ppos  = (int*)(ws + OFF_PPOS);

  hipMemsetAsync(ws + OFF_CNT, 0, 128, stream);

  cvt_x_kernel<<<(T_TOK * H_DIM / 8) / 256, 256, 0, stream>>>(x, xb);
  tconv_kernel<<<dim3(I_DIM / 64, H_DIM / 64, E_NUM), 256, 0, stream>>>(wg, wgt, H_DIM, I_DIM);
  tconv_kernel<<<dim3(I_DIM / 64, H_DIM / 64, E_NUM), 256, 0, stream>>>(wu, wut, H_DIM, I_DIM);
  router_kernel<<<T_TOK / 4, 256, 0, stream>>>(x, rw, logits, sel, wts);
  hist_kernel<<<(T_TOK * TOPK) / 256, 256, 0, stream>>>(sel, cnt);
  prefix_kernel<<<1, 64, 0, stream>>>(cnt, offs, curs);
  scatter_kernel<<<(T_TOK * TOPK) / 256, 256, 0, stream>>>(sel, wts, curs, rtok, rwt, ppos);
  gemm1_kernel<<<dim3(I_DIM / 64, 16, E_NUM), 256, 0, stream>>>(xb, wgt, wut, cnt, offs, rtok, rwt, abuf);
  tconv_kernel<<<dim3(H_DIM / 64, I_DIM / 64, E_NUM), 256, 0, stream>>>(wd, wdt, I_DIM, H_DIM);
  gemm2_kernel<<<dim3(H_DIM / 128, 16, E_NUM), 256, 0, stream>>>(abuf, wdt, cnt, offs, pbuf);
  combine_kernel<<<(T_TOK * (H_DIM / 4)) / 256, 256, 0, stream>>>(pbuf, ppos, out);
}

// Round 4
// 324.426 us; speedup vs baseline: 1.9369x; 1.2088x over previous
//
#include <hip/hip_runtime.h>
#include <hip/hip_bf16.h>

#define H_DIM 2048
#define T_TOK 2048
#define E_NUM 16
#define I_DIM 1024
#define TOPK  4

typedef short short8v __attribute__((ext_vector_type(8)));
typedef float f32x4v __attribute__((ext_vector_type(4)));
typedef unsigned short u16;
typedef unsigned int u32;

// ---------- ws layout (bytes) ----------
constexpr size_t OFF_XB   = 0;                                     // 8 MiB
constexpr size_t OFF_ABUF = OFF_XB   + (size_t)T_TOK*H_DIM*2;      // 16 MiB
constexpr size_t OFF_PBUF = OFF_ABUF + (size_t)T_TOK*TOPK*I_DIM*2; // 64 MiB
constexpr size_t OFF_SEL  = OFF_PBUF + (size_t)T_TOK*TOPK*H_DIM*4;
constexpr size_t OFF_WTS  = OFF_SEL  + (size_t)T_TOK*TOPK*4;
constexpr size_t OFF_CNT  = OFF_WTS  + (size_t)T_TOK*TOPK*4;
constexpr size_t OFF_OFFS = OFF_CNT  + 128;
constexpr size_t OFF_CURS = OFF_OFFS + 128;
constexpr size_t OFF_RTOK = OFF_CURS + 128;
constexpr size_t OFF_RWT  = OFF_RTOK + (size_t)T_TOK*TOPK*4;
constexpr size_t OFF_PPOS = OFF_RWT  + (size_t)T_TOK*TOPK*4;
constexpr size_t WS_NEED  = OFF_PPOS + (size_t)T_TOK*TOPK*4;

// ---------- helpers ----------
__device__ __forceinline__ u16 f2b(float f) {   // fp32 -> bf16 RNE
  u32 u = __builtin_bit_cast(u32, f);
  u32 r = (u + 0x7FFFu + ((u >> 16) & 1u)) >> 16;
  return (u16)r;
}

// v_cvt_pk_bf16_f32: dst.lo = bf16(lo), dst.hi = bf16(hi)  (T12 recipe, gfx950)
__device__ __forceinline__ u32 cvtpk(float lo, float hi) {
  u32 r;
  asm("v_cvt_pk_bf16_f32 %0, %1, %2" : "=v"(r) : "v"(lo), "v"(hi));
  return r;
}

__device__ __forceinline__ void gld16(const void* g, void* l) {
  __builtin_amdgcn_global_load_lds(
      (const __attribute__((address_space(1))) u32*)g,
      (__attribute__((address_space(3))) u32*)l, 16, 0, 0);
}

// ---------- fp32 -> bf16 (x) ----------
__global__ __launch_bounds__(256) void cvt_x_kernel(const float* __restrict__ src,
                                                    u16* __restrict__ dst) {
  int i = blockIdx.x * 256 + threadIdx.x;
  const float4* s = (const float4*)src + (size_t)i * 2;
  float4 a = s[0], b = s[1];
  uint4 o;
  o.x = (u32)f2b(a.x) | ((u32)f2b(a.y) << 16);
  o.y = (u32)f2b(a.z) | ((u32)f2b(a.w) << 16);
  o.z = (u32)f2b(b.x) | ((u32)f2b(b.y) << 16);
  o.w = (u32)f2b(b.z) | ((u32)f2b(b.w) << 16);
  ((uint4*)dst)[i] = o;
}

// ---------- router: vectorized fp32 logits, top-4, softmax ----------
__global__ __launch_bounds__(256) void router_kernel(const float* __restrict__ x,
                                                     const float* __restrict__ rw,
                                                     float* __restrict__ logits,
                                                     int* __restrict__ sel,
                                                     float* __restrict__ wts) {
  int w = threadIdx.x >> 6, lane = threadIdx.x & 63;
  int t = blockIdx.x * 4 + w;

  const float4* xt = (const float4*)(x + (size_t)t * H_DIM);
  float4 xv[8];
  #pragma unroll
  for (int j = 0; j < 8; ++j) xv[j] = xt[j * 64 + lane];

  const float4* rw4 = (const float4*)rw;
  float le[E_NUM];
  #pragma unroll
  for (int e = 0; e < E_NUM; ++e) {
    float s = 0.f;
    #pragma unroll
    for (int j = 0; j < 8; ++j) {
      float4 wv = rw4[e * (H_DIM / 4) + j * 64 + lane];
      s += xv[j].x * wv.x + xv[j].y * wv.y + xv[j].z * wv.z + xv[j].w * wv.w;
    }
    #pragma unroll
    for (int off = 32; off; off >>= 1) s += __shfl_xor(s, off);
    le[e] = s;
  }

  int taken = 0;
  float tv[TOPK]; int ti[TOPK];
  #pragma unroll
  for (int k = 0; k < TOPK; ++k) {
    float bv = -1e30f; int bi = 0;
    #pragma unroll
    for (int e = 0; e < E_NUM; ++e) {
      bool ok = !(taken & (1 << e));
      if (ok && le[e] > bv) { bv = le[e]; bi = e; }
    }
    taken |= (1 << bi); tv[k] = bv; ti[k] = bi;
  }
  float m = tv[0];
  float ew[TOPK]; float ssum = 0.f;
  #pragma unroll
  for (int k = 0; k < TOPK; ++k) { ew[k] = __expf(tv[k] - m); ssum += ew[k]; }
  if (lane == 0) {
    #pragma unroll
    for (int e = 0; e < E_NUM; ++e) logits[(size_t)t * E_NUM + e] = le[e];
    float inv = 1.f / ssum;
    #pragma unroll
    for (int k = 0; k < TOPK; ++k) {
      sel[t * TOPK + k] = ti[k];
      wts[t * TOPK + k] = ew[k] * inv;
    }
  }
}

// ---------- grouping ----------
__global__ void hist_kernel(const int* __restrict__ sel, int* __restrict__ cnt) {
  int p = blockIdx.x * 256 + threadIdx.x;
  if (p < T_TOK * TOPK) atomicAdd(&cnt[sel[p]], 1);
}

__global__ void prefix_kernel(const int* __restrict__ cnt, int* __restrict__ offs,
                              int* __restrict__ curs) {
  if (threadIdx.x == 0) {
    int a = 0;
    for (int e = 0; e < E_NUM; ++e) { offs[e] = a; curs[e] = a; a += cnt[e]; }
    offs[E_NUM] = a;
  }
}

__global__ void scatter_kernel(const int* __restrict__ sel, const float* __restrict__ wts,
                               int* __restrict__ curs, int* __restrict__ rtok,
                               float* __restrict__ rwt, int* __restrict__ ppos) {
  int p = blockIdx.x * 256 + threadIdx.x;
  if (p >= T_TOK * TOPK) return;
  int e = sel[p];
  int pos = atomicAdd(&curs[e], 1);
  rtok[pos] = p >> 2;
  rwt[pos] = wts[p];
  ppos[p] = pos;
}

// ---------- GEMM1: x @ [gate ; up] (fp32 weights, fused cvt) -> silu*up*wt -> abuf ----------
// 128M x (64+64)N tile, BK=64, double-buffered 2-phase:
//   issue A-gld16(next) + B-f32-loads(next) -> MFMA(cur) -> cvt+ds_write B(next) -> barrier.
// B staged from native (E,H,I) layout: lane owns I-col, loads 16 k-strided f32
// (wave-coalesced 256B rows), transpose happens at the swizzled ds_write_b128.
__global__ __launch_bounds__(256) void gemm1_kernel(
    const u16* __restrict__ xb, const float* __restrict__ wg, const float* __restrict__ wu,
    const int* __restrict__ cnt, const int* __restrict__ offs,
    const int* __restrict__ rtok, const float* __restrict__ rwt,
    u16* __restrict__ abuf) {
  int e = blockIdx.z;
  int cntE = cnt[e];
  int m0 = blockIdx.y * 128;
  if (m0 >= cntE) return;
  int n0 = blockIdx.x * 64;
  int base = offs[e];

  __shared__ alignas(16) char smem[4 * 16384 + 1024];   // A[2] | B[2] | tok | wt
  char* As0 = smem;
  char* Bs0 = smem + 32768;
  int* tokloc = (int*)(smem + 65536);
  float* wtloc = (float*)(smem + 65536 + 512);

  int tid = threadIdx.x;
  for (int i = tid; i < 128; i += 256) {
    int p = m0 + i;
    int pp = (p < cntE) ? p : (cntE - 1);
    tokloc[i] = rtok[base + pp];
    wtloc[i] = (p < cntE) ? rwt[base + pp] : 0.f;
  }
  __syncthreads();

  int lane = tid & 63;
  int w = tid >> 6;
  int wr = (w >> 1) * 64, wc = (w & 1) * 32;
  int ln15 = lane & 15, g4 = lane >> 4;

  // A staging (gld16, linear LDS dest + inverse-swizzled source)
  const u16* aptr[4]; int soff[4];
  #pragma unroll
  for (int it = 0; it < 4; ++it) {
    int s = it * 256 + tid;
    int row = s >> 3;
    int c16 = (s & 7) ^ (row & 7);
    soff[it] = s * 16;
    aptr[it] = xb + (size_t)tokloc[row] * H_DIM + c16 * 8;
  }

  // B staging (reg): lane = I-col bi; rows btg*16..+15 of the K-step
  int bi = tid & 63;
  int btg = tid >> 6;
  const float* gbase = wg + ((size_t)e * H_DIM + btg * 16) * I_DIM + n0 + bi;
  const float* ubase = wu + ((size_t)e * H_DIM + btg * 16) * I_DIM + n0 + bi;
  int bws0 = bi * 128 + (((btg * 2 + 0) ^ (bi & 7)) << 4);
  int bws1 = bi * 128 + (((btg * 2 + 1) ^ (bi & 7)) << 4);

  // fragment row offsets
  int aoff[4], boff[4];
  #pragma unroll
  for (int m = 0; m < 4; ++m) aoff[m] = (wr + m * 16 + ln15) * 128;
  #pragma unroll
  for (int n = 0; n < 4; ++n) {
    int brow = (n < 2) ? (wc + n * 16 + ln15) : (64 + wc + (n - 2) * 16 + ln15);
    boff[n] = brow * 128;
  }
  int xk0 = ((g4) ^ (lane & 7)) << 4;
  int xk1 = ((4 + g4) ^ (lane & 7)) << 4;

  f32x4v acc[4][4];
  #pragma unroll
  for (int m = 0; m < 4; ++m)
    #pragma unroll
    for (int n = 0; n < 4; ++n) acc[m][n] = f32x4v{0, 0, 0, 0};

  // ---- prologue: stage kb=0 into buf0 ----
  #pragma unroll
  for (int it = 0; it < 4; ++it) gld16(aptr[it], As0 + soff[it]);
  {
    float gv[16], uv[16];
    #pragma unroll
    for (int r = 0; r < 16; ++r) {
      gv[r] = gbase[(size_t)r * I_DIM];
      uv[r] = ubase[(size_t)r * I_DIM];
    }
    uint4 g0{cvtpk(gv[0],gv[1]), cvtpk(gv[2],gv[3]), cvtpk(gv[4],gv[5]), cvtpk(gv[6],gv[7])};
    uint4 g1{cvtpk(gv[8],gv[9]), cvtpk(gv[10],gv[11]), cvtpk(gv[12],gv[13]), cvtpk(gv[14],gv[15])};
    uint4 u0{cvtpk(uv[0],uv[1]), cvtpk(uv[2],uv[3]), cvtpk(uv[4],uv[5]), cvtpk(uv[6],uv[7])};
    uint4 u1{cvtpk(uv[8],uv[9]), cvtpk(uv[10],uv[11]), cvtpk(uv[12],uv[13]), cvtpk(uv[14],uv[15])};
    *(uint4*)(Bs0 + bws0) = g0;
    *(uint4*)(Bs0 + bws1) = g1;
    *(uint4*)(Bs0 + 8192 + bws0) = u0;
    *(uint4*)(Bs0 + 8192 + bws1) = u1;
  }
  __syncthreads();

  int cur = 0;
  for (int kb = 0; kb < H_DIM; kb += 64) {
    bool hn = (kb + 64) < H_DIM;
    float gv[16], uv[16];
    if (hn) {
      char* Asn = As0 + ((cur ^ 1) << 14);
      #pragma unroll
      for (int it = 0; it < 4; ++it) gld16(aptr[it] + kb + 64, Asn + soff[it]);
      const float* gs = gbase + (size_t)(kb + 64) * I_DIM;
      const float* us = ubase + (size_t)(kb + 64) * I_DIM;
      #pragma unroll
      for (int r = 0; r < 16; ++r) {
        gv[r] = gs[(size_t)r * I_DIM];
        uv[r] = us[(size_t)r * I_DIM];
      }
    }
    // compute current buffer
    char* Ac = As0 + (cur << 14);
    char* Bc = Bs0 + (cur << 14);
    #pragma unroll
    for (int kk = 0; kk < 2; ++kk) {
      int xo = kk ? xk1 : xk0;
      short8v a[4], b[4];
      #pragma unroll
      for (int m = 0; m < 4; ++m) a[m] = *(const short8v*)(Ac + aoff[m] + xo);
      #pragma unroll
      for (int n = 0; n < 4; ++n) b[n] = *(const short8v*)(Bc + boff[n] + xo);
      #pragma unroll
      for (int m = 0; m < 4; ++m)
        #pragma unroll
        for (int n = 0; n < 4; ++n)
          acc[m][n] = __builtin_amdgcn_mfma_f32_16x16x32_bf16(a[m], b[n], acc[m][n], 0, 0, 0);
    }
    if (hn) {
      char* Bn = Bs0 + ((cur ^ 1) << 14);
      uint4 g0{cvtpk(gv[0],gv[1]), cvtpk(gv[2],gv[3]), cvtpk(gv[4],gv[5]), cvtpk(gv[6],gv[7])};
      uint4 g1{cvtpk(gv[8],gv[9]), cvtpk(gv[10],gv[11]), cvtpk(gv[12],gv[13]), cvtpk(gv[14],gv[15])};
      uint4 u0{cvtpk(uv[0],uv[1]), cvtpk(uv[2],uv[3]), cvtpk(uv[4],uv[5]), cvtpk(uv[6],uv[7])};
      uint4 u1{cvtpk(uv[8],uv[9]), cvtpk(uv[10],uv[11]), cvtpk(uv[12],uv[13]), cvtpk(uv[14],uv[15])};
      *(uint4*)(Bn + bws0) = g0;
      *(uint4*)(Bn + bws1) = g1;
      *(uint4*)(Bn + 8192 + bws0) = u0;
      *(uint4*)(Bn + 8192 + bws1) = u1;
    }
    __syncthreads();
    cur ^= 1;
  }

  // epilogue: silu(g)*u*wt -> bf16
  #pragma unroll
  for (int m = 0; m < 4; ++m) {
    #pragma unroll
    for (int r = 0; r < 4; ++r) {
      int row = wr + m * 16 + g4 * 4 + r;
      if (m0 + row < cntE) {
        float wt = wtloc[row];
        size_t orow = (size_t)(base + m0 + row) * I_DIM + n0 + wc;
        #pragma unroll
        for (int j = 0; j < 2; ++j) {
          float g = acc[m][j][r], u = acc[m][j + 2][r];
          float aa = g / (1.f + __expf(-g)) * u * wt;
          abuf[orow + j * 16 + ln15] = f2b(aa);
        }
      }
    }
  }
}

// ---------- GEMM2: abuf @ w_down (fp32, fused cvt) -> pbuf (f32 grouped rows) ----------
__global__ __launch_bounds__(256) void gemm2_kernel(
    const u16* __restrict__ abuf, const float* __restrict__ wd,
    const int* __restrict__ cnt, const int* __restrict__ offs,
    float* __restrict__ pbuf) {
  int e = blockIdx.z;
  int cntE = cnt[e];
  int m0 = blockIdx.y * 128;
  if (m0 >= cntE) return;
  int n0 = blockIdx.x * 128;
  int base = offs[e];

  __shared__ alignas(16) char smem[4 * 16384];   // A[2] | B[2]
  char* As0 = smem;
  char* Bs0 = smem + 32768;

  int tid = threadIdx.x;
  int lane = tid & 63;
  int w = tid >> 6;
  int wr = (w >> 1) * 64, wc = (w & 1) * 64;
  int ln15 = lane & 15, g4 = lane >> 4;

  // A staging (gld16): grouped rows, no gather
  const u16* aptr[4]; int soff[4];
  #pragma unroll
  for (int it = 0; it < 4; ++it) {
    int s = it * 256 + tid;
    int row = s >> 3;
    int c16 = (s & 7) ^ (row & 7);
    soff[it] = s * 16;
    int p = m0 + row;
    int pp = (p < cntE) ? p : (cntE - 1);
    aptr[it] = abuf + (size_t)(base + pp) * I_DIM + c16 * 8;
  }

  // B staging (reg): lane = H-col bj (0..127 across 2 wave-pairs); rows btg*32..+31
  int bj = tid & 127;
  int btg = tid >> 7;
  const float* dbase = wd + ((size_t)e * I_DIM + btg * 32) * H_DIM + n0 + bj;
  int bws[4];
  #pragma unroll
  for (int s = 0; s < 4; ++s) bws[s] = bj * 128 + (((btg * 4 + s) ^ (bj & 7)) << 4);

  int aoff[4], boff[4];
  #pragma unroll
  for (int m = 0; m < 4; ++m) aoff[m] = (wr + m * 16 + ln15) * 128;
  #pragma unroll
  for (int n = 0; n < 4; ++n) boff[n] = (wc + n * 16 + ln15) * 128;
  int xk0 = ((g4) ^ (lane & 7)) << 4;
  int xk1 = ((4 + g4) ^ (lane & 7)) << 4;

  f32x4v acc[4][4];
  #pragma unroll
  for (int m = 0; m < 4; ++m)
    #pragma unroll
    for (int n = 0; n < 4; ++n) acc[m][n] = f32x4v{0, 0, 0, 0};

  // prologue
  #pragma unroll
  for (int it = 0; it < 4; ++it) gld16(aptr[it], As0 + soff[it]);
  {
    float dv[32];
    #pragma unroll
    for (int r = 0; r < 32; ++r) dv[r] = dbase[(size_t)r * H_DIM];
    #pragma unroll
    for (int s = 0; s < 4; ++s) {
      uint4 v{cvtpk(dv[8*s+0],dv[8*s+1]), cvtpk(dv[8*s+2],dv[8*s+3]),
              cvtpk(dv[8*s+4],dv[8*s+5]), cvtpk(dv[8*s+6],dv[8*s+7])};
      *(uint4*)(Bs0 + bws[s]) = v;
    }
  }
  __syncthreads();

  int cur = 0;
  for (int kb = 0; kb < I_DIM; kb += 64) {
    bool hn = (kb + 64) < I_DIM;
    float dv[32];
    if (hn) {
      char* Asn = As0 + ((cur ^ 1) << 14);
      #pragma unroll
      for (int it = 0; it < 4; ++it) gld16(aptr[it] + kb + 64, Asn + soff[it]);
      const float* ds = dbase + (size_t)(kb + 64) * H_DIM;
      #pragma unroll
      for (int r = 0; r < 32; ++r) dv[r] = ds[(size_t)r * H_DIM];
    }
    char* Ac = As0 + (cur << 14);
    char* Bc = Bs0 + (cur << 14);
    #pragma unroll
    for (int kk = 0; kk < 2; ++kk) {
      int xo = kk ? xk1 : xk0;
      short8v a[4], b[4];
      #pragma unroll
      for (int m = 0; m < 4; ++m) a[m] = *(const short8v*)(Ac + aoff[m] + xo);
      #pragma unroll
      for (int n = 0; n < 4; ++n) b[n] = *(const short8v*)(Bc + boff[n] + xo);
      #pragma unroll
      for (int m = 0; m < 4; ++m)
        #pragma unroll
        for (int n = 0; n < 4; ++n)
          acc[m][n] = __builtin_amdgcn_mfma_f32_16x16x32_bf16(a[m], b[n], acc[m][n], 0, 0, 0);
    }
    if (hn) {
      char* Bn = Bs0 + ((cur ^ 1) << 14);
      #pragma unroll
      for (int s = 0; s < 4; ++s) {
        uint4 v{cvtpk(dv[8*s+0],dv[8*s+1]), cvtpk(dv[8*s+2],dv[8*s+3]),
                cvtpk(dv[8*s+4],dv[8*s+5]), cvtpk(dv[8*s+6],dv[8*s+7])};
        *(uint4*)(Bn + bws[s]) = v;
      }
    }
    __syncthreads();
    cur ^= 1;
  }

  #pragma unroll
  for (int m = 0; m < 4; ++m) {
    #pragma unroll
    for (int r = 0; r < 4; ++r) {
      int row = wr + m * 16 + g4 * 4 + r;
      if (m0 + row < cntE) {
        float* orow = pbuf + (size_t)(base + m0 + row) * H_DIM + n0 + wc;
        #pragma unroll
        for (int n = 0; n < 4; ++n)
          orow[n * 16 + ln15] = acc[m][n][r];
      }
    }
  }
}

// ---------- combine: out[t] = sum_k pbuf[ppos[t][k]] ----------
__global__ __launch_bounds__(256) void combine_kernel(const float* __restrict__ pbuf,
                                                      const int* __restrict__ ppos,
                                                      float* __restrict__ out) {
  int idx = blockIdx.x * 256 + threadIdx.x;     // over T * (H/4)
  int t = idx >> 9;
  int h4 = (idx & 511) * 4;
  int4 pp = ((const int4*)ppos)[t];
  float4 s0 = *(const float4*)&pbuf[(size_t)pp.x * H_DIM + h4];
  float4 s1 = *(const float4*)&pbuf[(size_t)pp.y * H_DIM + h4];
  float4 s2 = *(const float4*)&pbuf[(size_t)pp.z * H_DIM + h4];
  float4 s3 = *(const float4*)&pbuf[(size_t)pp.w * H_DIM + h4];
  float4 o;
  o.x = s0.x + s1.x + s2.x + s3.x;
  o.y = s0.y + s1.y + s2.y + s3.y;
  o.z = s0.z + s1.z + s2.z + s3.z;
  o.w = s0.w + s1.w + s2.w + s3.w;
  *(float4*)&out[(size_t)t * H_DIM + h4] = o;
}

// ---------- launch ----------
extern "C" void kernel_launch(void* const* d_in, const int* in_sizes, int n_in,
                              void* d_out, int out_size, void* d_ws, size_t ws_size,
                              hipStream_t stream) {
  (void)in_sizes; (void)n_in; (void)out_size;
  if (ws_size < WS_NEED) return;

  const float* x  = (const float*)d_in[0];
  const float* rw = (const float*)d_in[1];
  const float* wg = (const float*)d_in[2];
  const float* wu = (const float*)d_in[3];
  const float* wd = (const float*)d_in[4];
  float* out = (float*)d_out;
  float* logits = out + (size_t)T_TOK * H_DIM;

  char* ws = (char*)d_ws;
  u16* xb    = (u16*)(ws + OFF_XB);
  u16* abuf  = (u16*)(ws + OFF_ABUF);
  float* pbuf = (float*)(ws + OFF_PBUF);
  int* sel   = (int*)(ws + OFF_SEL);
  float* wts = (float*)(ws + OFF_WTS);
  int* cnt   = (int*)(ws + OFF_CNT);
  int* offs  = (int*)(ws + OFF_OFFS);
  int* curs  = (int*)(ws + OFF_CURS);
  int* rtok  = (int*)(ws + OFF_RTOK);
  float* rwt = (float*)(ws + OFF_RWT);
  int* ppos  = (int*)(ws + OFF_PPOS);

  hipMemsetAsync(ws + OFF_CNT, 0, 128, stream);

  cvt_x_kernel<<<(T_TOK * H_DIM / 8) / 256, 256, 0, stream>>>(x, xb);
  router_kernel<<<T_TOK / 4, 256, 0, stream>>>(x, rw, logits, sel, wts);
  hist_kernel<<<(T_TOK * TOPK) / 256, 256, 0, stream>>>(sel, cnt);
  prefix_kernel<<<1, 64, 0, stream>>>(cnt, offs, curs);
  scatter_kernel<<<(T_TOK * TOPK) / 256, 256, 0, stream>>>(sel, wts, curs, rtok, rwt, ppos);
  gemm1_kernel<<<dim3(I_DIM / 64, 16, E_NUM), 256, 0, stream>>>(xb, wg, wu, cnt, offs, rtok, rwt, abuf);
  gemm2_kernel<<<dim3(H_DIM / 128, 16, E_NUM), 256, 0, stream>>>(abuf, wd, cnt, offs, pbuf);
  combine_kernel<<<(T_TOK * (H_DIM / 4)) / 256, 256, 0, stream>>>(pbuf, ppos, out);
}

// Round 5
// 313.034 us; speedup vs baseline: 2.0074x; 1.0364x over previous
//
#include <hip/hip_runtime.h>
#include <hip/hip_bf16.h>

#define H_DIM 2048
#define T_TOK 2048
#define E_NUM 16
#define I_DIM 1024
#define TOPK  4
#define NK1   32   // H_DIM/64
#define NK2   16   // I_DIM/64

typedef short short8v __attribute__((ext_vector_type(8)));
typedef float f32x4v __attribute__((ext_vector_type(4)));
typedef unsigned short u16;
typedef unsigned int u32;

// ---------- ws layout (bytes) ----------
constexpr size_t OFF_XB   = 0;                                     // 8 MiB
constexpr size_t OFF_ABUF = OFF_XB   + (size_t)T_TOK*H_DIM*2;      // 16 MiB
constexpr size_t OFF_PBUF = OFF_ABUF + (size_t)T_TOK*TOPK*I_DIM*2; // 64 MiB
constexpr size_t OFF_SEL  = OFF_PBUF + (size_t)T_TOK*TOPK*H_DIM*4;
constexpr size_t OFF_WTS  = OFF_SEL  + (size_t)T_TOK*TOPK*4;
constexpr size_t OFF_CNT  = OFF_WTS  + (size_t)T_TOK*TOPK*4;
constexpr size_t OFF_OFFS = OFF_CNT  + 128;
constexpr size_t OFF_CURS = OFF_OFFS + 128;
constexpr size_t OFF_RTOK = OFF_CURS + 128;
constexpr size_t OFF_RWT  = OFF_RTOK + (size_t)T_TOK*TOPK*4;
constexpr size_t OFF_PPOS = OFF_RWT  + (size_t)T_TOK*TOPK*4;
constexpr size_t WS_NEED  = OFF_PPOS + (size_t)T_TOK*TOPK*4;

// ---------- helpers ----------
__device__ __forceinline__ u16 f2b(float f) {   // fp32 -> bf16 RNE
  u32 u = __builtin_bit_cast(u32, f);
  u32 r = (u + 0x7FFFu + ((u >> 16) & 1u)) >> 16;
  return (u16)r;
}

__device__ __forceinline__ u32 cvtpk(float lo, float hi) {
  u32 r;
  asm("v_cvt_pk_bf16_f32 %0, %1, %2" : "=v"(r) : "v"(lo), "v"(hi));
  return r;
}

__device__ __forceinline__ void gld16(const void* g, void* l) {
  __builtin_amdgcn_global_load_lds(
      (const __attribute__((address_space(1))) u32*)g,
      (__attribute__((address_space(3))) u32*)l, 16, 0, 0);
}

#define SB0 __builtin_amdgcn_sched_barrier(0)
// counted-vmcnt barrier: loads (N outstanding allowed) survive the barrier (T3/T4)
#define WAITBAR8 { SB0; asm volatile("s_waitcnt vmcnt(8) lgkmcnt(0)" ::: "memory"); \
                   __builtin_amdgcn_s_barrier(); SB0; }
#define WAITBAR0 { SB0; asm volatile("s_waitcnt vmcnt(0) lgkmcnt(0)" ::: "memory"); \
                   __builtin_amdgcn_s_barrier(); SB0; }

// ---------- fp32 -> bf16 (x) ----------
__global__ __launch_bounds__(256) void cvt_x_kernel(const float* __restrict__ src,
                                                    u16* __restrict__ dst) {
  int i = blockIdx.x * 256 + threadIdx.x;
  const float4* s = (const float4*)src + (size_t)i * 2;
  float4 a = s[0], b = s[1];
  uint4 o;
  o.x = (u32)f2b(a.x) | ((u32)f2b(a.y) << 16);
  o.y = (u32)f2b(a.z) | ((u32)f2b(a.w) << 16);
  o.z = (u32)f2b(b.x) | ((u32)f2b(b.y) << 16);
  o.w = (u32)f2b(b.z) | ((u32)f2b(b.w) << 16);
  ((uint4*)dst)[i] = o;
}

// ---------- router ----------
__global__ __launch_bounds__(256) void router_kernel(const float* __restrict__ x,
                                                     const float* __restrict__ rw,
                                                     float* __restrict__ logits,
                                                     int* __restrict__ sel,
                                                     float* __restrict__ wts) {
  int w = threadIdx.x >> 6, lane = threadIdx.x & 63;
  int t = blockIdx.x * 4 + w;

  const float4* xt = (const float4*)(x + (size_t)t * H_DIM);
  float4 xv[8];
  #pragma unroll
  for (int j = 0; j < 8; ++j) xv[j] = xt[j * 64 + lane];

  const float4* rw4 = (const float4*)rw;
  float le[E_NUM];
  #pragma unroll
  for (int e = 0; e < E_NUM; ++e) {
    float s = 0.f;
    #pragma unroll
    for (int j = 0; j < 8; ++j) {
      float4 wv = rw4[e * (H_DIM / 4) + j * 64 + lane];
      s += xv[j].x * wv.x + xv[j].y * wv.y + xv[j].z * wv.z + xv[j].w * wv.w;
    }
    #pragma unroll
    for (int off = 32; off; off >>= 1) s += __shfl_xor(s, off);
    le[e] = s;
  }

  int taken = 0;
  float tv[TOPK]; int ti[TOPK];
  #pragma unroll
  for (int k = 0; k < TOPK; ++k) {
    float bv = -1e30f; int bi = 0;
    #pragma unroll
    for (int e = 0; e < E_NUM; ++e) {
      bool ok = !(taken & (1 << e));
      if (ok && le[e] > bv) { bv = le[e]; bi = e; }
    }
    taken |= (1 << bi); tv[k] = bv; ti[k] = bi;
  }
  float m = tv[0];
  float ew[TOPK]; float ssum = 0.f;
  #pragma unroll
  for (int k = 0; k < TOPK; ++k) { ew[k] = __expf(tv[k] - m); ssum += ew[k]; }
  if (lane == 0) {
    #pragma unroll
    for (int e = 0; e < E_NUM; ++e) logits[(size_t)t * E_NUM + e] = le[e];
    float inv = 1.f / ssum;
    #pragma unroll
    for (int k = 0; k < TOPK; ++k) {
      sel[t * TOPK + k] = ti[k];
      wts[t * TOPK + k] = ew[k] * inv;
    }
  }
}

// ---------- grouping ----------
__global__ void hist_kernel(const int* __restrict__ sel, int* __restrict__ cnt) {
  int p = blockIdx.x * 256 + threadIdx.x;
  if (p < T_TOK * TOPK) atomicAdd(&cnt[sel[p]], 1);
}

__global__ void prefix_kernel(const int* __restrict__ cnt, int* __restrict__ offs,
                              int* __restrict__ curs) {
  if (threadIdx.x == 0) {
    int a = 0;
    for (int e = 0; e < E_NUM; ++e) { offs[e] = a; curs[e] = a; a += cnt[e]; }
    offs[E_NUM] = a;
  }
}

__global__ void scatter_kernel(const int* __restrict__ sel, const float* __restrict__ wts,
                               int* __restrict__ curs, int* __restrict__ rtok,
                               float* __restrict__ rwt, int* __restrict__ ppos) {
  int p = blockIdx.x * 256 + threadIdx.x;
  if (p >= T_TOK * TOPK) return;
  int e = sel[p];
  int pos = atomicAdd(&curs[e], 1);
  rtok[pos] = p >> 2;
  rwt[pos] = wts[p];
  ppos[p] = pos;
}

// ================= GEMM1: x @ [gate ; up] -> silu(g)*u*wt -> abuf (bf16) ==========
// 128M x (64g+64u)N tile, BK=64. Raw-barrier pipeline: A gld16 1-deep, B fp32
// float4-loads 2-deep (issued k+2) -> cvtpk -> swizzled ds_write (k+1) each iter.
// Steady-state vmcnt invariant after each barrier: exactly B(k+2)x8 outstanding.
__global__ __launch_bounds__(256) void gemm1_kernel(
    const u16* __restrict__ xb, const float* __restrict__ wg, const float* __restrict__ wu,
    const int* __restrict__ cnt, const int* __restrict__ offs,
    const int* __restrict__ rtok, const float* __restrict__ rwt,
    u16* __restrict__ abuf) {
  int e = blockIdx.z;
  int cntE = cnt[e];
  int m0 = blockIdx.y * 128;
  if (m0 >= cntE) return;
  int n0 = blockIdx.x * 64;
  int base = offs[e];

  __shared__ alignas(16) char smem[65536 + 1024];
  char* A0lds = smem;
  char* A1lds = smem + 16384;
  char* B0lds = smem + 32768;
  char* B1lds = smem + 49152;
  int* tokloc = (int*)(smem + 65536);
  float* wtloc = (float*)(smem + 65536 + 512);

  int tid = threadIdx.x;
  for (int i = tid; i < 128; i += 256) {
    int p = m0 + i;
    int pp = (p < cntE) ? p : (cntE - 1);
    tokloc[i] = rtok[base + pp];
    wtloc[i] = (p < cntE) ? rwt[base + pp] : 0.f;
  }
  __syncthreads();

  int lane = tid & 63;
  int w = tid >> 6;
  int wr = (w >> 1) * 64, wc = (w & 1) * 32;
  int ln15 = lane & 15, g4 = lane >> 4;

  // A staging (gld16, linear LDS dest + inverse-swizzled source)
  const u16* aptr[4]; int soff[4];
  #pragma unroll
  for (int it = 0; it < 4; ++it) {
    int s = it * 256 + tid;
    int row = s >> 3;
    int c16 = (s & 7) ^ (row & 7);
    soff[it] = s * 16;
    aptr[it] = xb + (size_t)tokloc[row] * H_DIM + c16 * 8;
  }

  // B staging mapping: lane covers (rows w*16+{2br,2br+1,8+2br,9+2br}, cols bc4..+3)
  int br = lane >> 4;
  int bc4 = (lane & 15) * 4;
  const float* wge = wg + (size_t)e * H_DIM * I_DIM + n0 + bc4;
  const float* wue = wu + (size_t)e * H_DIM * I_DIM + n0 + bc4;
  int kb4 = 4 * br;       // byte-in-slot
  int ks0 = w * 2;        // k-slot base (even)

  // fragment read offsets
  int aoff[4];
  #pragma unroll
  for (int m = 0; m < 4; ++m) aoff[m] = (wr + m * 16 + ln15) * 128;
  int bro[4], rs4[4];
  #pragma unroll
  for (int n = 0; n < 4; ++n) {
    int brow = (n < 2) ? (wc + n * 16 + ln15) : (64 + wc + (n - 2) * 16 + ln15);
    bro[n] = brow * 128;
    rs4[n] = ((brow ^ (brow >> 3)) & 7) << 4;
  }
  int la7_4 = (lane & 7) << 4;

  f32x4v acc[4][4];
  #pragma unroll
  for (int m = 0; m < 4; ++m)
    #pragma unroll
    for (int n = 0; n < 4; ++n) acc[m][n] = f32x4v{0, 0, 0, 0};

  float4 gv0[4], uv0[4], gv1[4], uv1[4];

#define G1_ISSA(kq, AB) { \
  _Pragma("unroll") for (int it = 0; it < 4; ++it) \
    gld16(aptr[it] + (size_t)(kq) * 64, (AB) + soff[it]); }

#define G1_LOADB(S, kq) { \
  const float* _g = wge + (size_t)((kq) * 64 + w * 16 + 2 * br) * I_DIM; \
  const float* _u = wue + (size_t)((kq) * 64 + w * 16 + 2 * br) * I_DIM; \
  gv##S[0] = *(const float4*)(_g); \
  gv##S[1] = *(const float4*)(_g + I_DIM); \
  gv##S[2] = *(const float4*)(_g + 8 * I_DIM); \
  gv##S[3] = *(const float4*)(_g + 9 * I_DIM); \
  uv##S[0] = *(const float4*)(_u); \
  uv##S[1] = *(const float4*)(_u + I_DIM); \
  uv##S[2] = *(const float4*)(_u + 8 * I_DIM); \
  uv##S[3] = *(const float4*)(_u + 9 * I_DIM); }

#define G1_CVTW(S, BUF) { \
  _Pragma("unroll") for (int p = 0; p < 2; ++p) { \
    int _s16 = (ks0 ^ p) << 4; \
    _Pragma("unroll") for (int ii = 0; ii < 4; ++ii) { \
      int ig = bc4 + ii, iu = 64 + bc4 + ii; \
      u32 vg = cvtpk((&gv##S[p * 2].x)[ii], (&gv##S[p * 2 + 1].x)[ii]); \
      u32 vu = cvtpk((&uv##S[p * 2].x)[ii], (&uv##S[p * 2 + 1].x)[ii]); \
      *(u32*)((BUF) + ig * 128 + (_s16 ^ ((((ig ^ (ig >> 3)) & 7)) << 4)) + kb4) = vg; \
      *(u32*)((BUF) + iu * 128 + (_s16 ^ ((((iu ^ (iu >> 3)) & 7)) << 4)) + kb4) = vu; \
    } } }

#define G1_MFMA(AB, BB) { \
  _Pragma("unroll") for (int kk = 0; kk < 2; ++kk) { \
    int xo = (kk * 4 + g4) << 4; \
    short8v a[4], b[4]; \
    _Pragma("unroll") for (int m = 0; m < 4; ++m) \
      a[m] = *(const short8v*)((AB) + aoff[m] + (xo ^ la7_4)); \
    _Pragma("unroll") for (int n = 0; n < 4; ++n) \
      b[n] = *(const short8v*)((BB) + bro[n] + (xo ^ rs4[n])); \
    _Pragma("unroll") for (int m = 0; m < 4; ++m) \
      _Pragma("unroll") for (int n = 0; n < 4; ++n) \
        acc[m][n] = __builtin_amdgcn_mfma_f32_16x16x32_bf16(a[m], b[n], acc[m][n], 0, 0, 0); \
  } }

  // ---- prologue: A(0), B(0), B(1); stage B(0) ----
  G1_ISSA(0, A0lds); SB0;
  G1_LOADB(0, 0);
  G1_LOADB(1, 1);
  G1_CVTW(0, B0lds);
  WAITBAR8;

  #pragma unroll 1
  for (int kq = 0; kq + 4 <= NK1; kq += 2) {
    // even body k=kq
    G1_ISSA(kq + 1, A1lds); SB0;
    G1_LOADB(0, kq + 2);
    G1_MFMA(A0lds, B0lds);
    G1_CVTW(1, B1lds);
    WAITBAR8;
    // odd body k=kq+1
    G1_ISSA(kq + 2, A0lds); SB0;
    G1_LOADB(1, kq + 3);
    G1_MFMA(A1lds, B1lds);
    G1_CVTW(0, B0lds);
    WAITBAR8;
  }
  // k = NK1-2 (even): no more B issues
  G1_ISSA(NK1 - 1, A1lds); SB0;
  G1_MFMA(A0lds, B0lds);
  G1_CVTW(1, B1lds);
  WAITBAR0;
  // k = NK1-1 (odd)
  G1_MFMA(A1lds, B1lds);

  // epilogue: silu(g)*u*wt -> bf16
  #pragma unroll
  for (int m = 0; m < 4; ++m) {
    #pragma unroll
    for (int r = 0; r < 4; ++r) {
      int row = wr + m * 16 + g4 * 4 + r;
      if (m0 + row < cntE) {
        float wt = wtloc[row];
        size_t orow = (size_t)(base + m0 + row) * I_DIM + n0 + wc;
        #pragma unroll
        for (int j = 0; j < 2; ++j) {
          float g = acc[m][j][r], u = acc[m][j + 2][r];
          float aa = g / (1.f + __expf(-g)) * u * wt;
          abuf[orow + j * 16 + ln15] = f2b(aa);
        }
      }
    }
  }
#undef G1_ISSA
#undef G1_LOADB
#undef G1_CVTW
#undef G1_MFMA
}

// ================= GEMM2: abuf @ w_down -> pbuf (f32 grouped rows) ================
__global__ __launch_bounds__(256) void gemm2_kernel(
    const u16* __restrict__ abuf, const float* __restrict__ wd,
    const int* __restrict__ cnt, const int* __restrict__ offs,
    float* __restrict__ pbuf) {
  int e = blockIdx.z;
  int cntE = cnt[e];
  int m0 = blockIdx.y * 128;
  if (m0 >= cntE) return;
  int n0 = blockIdx.x * 128;
  int base = offs[e];

  __shared__ alignas(16) char smem[65536];
  char* A0lds = smem;
  char* A1lds = smem + 16384;
  char* B0lds = smem + 32768;
  char* B1lds = smem + 49152;

  int tid = threadIdx.x;
  int lane = tid & 63;
  int w = tid >> 6;
  int wr = (w >> 1) * 64, wc = (w & 1) * 64;
  int ln15 = lane & 15, g4 = lane >> 4;

  const u16* aptr[4]; int soff[4];
  #pragma unroll
  for (int it = 0; it < 4; ++it) {
    int s = it * 256 + tid;
    int row = s >> 3;
    int c16 = (s & 7) ^ (row & 7);
    soff[it] = s * 16;
    int p = m0 + row;
    int pp = (p < cntE) ? p : (cntE - 1);
    aptr[it] = abuf + (size_t)(base + pp) * I_DIM + c16 * 8;
  }

  int br = lane >> 4;
  int bc4 = (lane & 15) * 4;
  const float* wde = wd + (size_t)e * I_DIM * H_DIM + n0 + bc4;
  int kb4 = 4 * br;
  int ks0 = w * 2;

  int aoff[4];
  #pragma unroll
  for (int m = 0; m < 4; ++m) aoff[m] = (wr + m * 16 + ln15) * 128;
  int bro[4], rs4[4];
  #pragma unroll
  for (int n = 0; n < 4; ++n) {
    int brow = wc + n * 16 + ln15;
    bro[n] = brow * 128;
    rs4[n] = ((brow ^ (brow >> 3)) & 7) << 4;
  }
  int la7_4 = (lane & 7) << 4;

  f32x4v acc[4][4];
  #pragma unroll
  for (int m = 0; m < 4; ++m)
    #pragma unroll
    for (int n = 0; n < 4; ++n) acc[m][n] = f32x4v{0, 0, 0, 0};

  float4 dv0[8], dv1[8];

#define G2_ISSA(kq, AB) { \
  _Pragma("unroll") for (int it = 0; it < 4; ++it) \
    gld16(aptr[it] + (size_t)(kq) * 64, (AB) + soff[it]); }

#define G2_LOADB(S, kq) { \
  const float* _d = wde + (size_t)((kq) * 64 + w * 16 + 2 * br) * H_DIM; \
  dv##S[0] = *(const float4*)(_d); \
  dv##S[1] = *(const float4*)(_d + 64); \
  dv##S[2] = *(const float4*)(_d + H_DIM); \
  dv##S[3] = *(const float4*)(_d + H_DIM + 64); \
  dv##S[4] = *(const float4*)(_d + 8 * H_DIM); \
  dv##S[5] = *(const float4*)(_d + 8 * H_DIM + 64); \
  dv##S[6] = *(const float4*)(_d + 9 * H_DIM); \
  dv##S[7] = *(const float4*)(_d + 9 * H_DIM + 64); }

#define G2_CVTW(S, BUF) { \
  _Pragma("unroll") for (int p = 0; p < 2; ++p) { \
    int _s16 = (ks0 ^ p) << 4; \
    _Pragma("unroll") for (int hb = 0; hb < 2; ++hb) { \
      _Pragma("unroll") for (int ii = 0; ii < 4; ++ii) { \
        int hl = hb * 64 + bc4 + ii; \
        u32 v = cvtpk((&dv##S[p * 4 + hb].x)[ii], (&dv##S[p * 4 + 2 + hb].x)[ii]); \
        *(u32*)((BUF) + hl * 128 + (_s16 ^ ((((hl ^ (hl >> 3)) & 7)) << 4)) + kb4) = v; \
      } } } }

#define G2_MFMA(AB, BB) { \
  _Pragma("unroll") for (int kk = 0; kk < 2; ++kk) { \
    int xo = (kk * 4 + g4) << 4; \
    short8v a[4], b[4]; \
    _Pragma("unroll") for (int m = 0; m < 4; ++m) \
      a[m] = *(const short8v*)((AB) + aoff[m] + (xo ^ la7_4)); \
    _Pragma("unroll") for (int n = 0; n < 4; ++n) \
      b[n] = *(const short8v*)((BB) + bro[n] + (xo ^ rs4[n])); \
    _Pragma("unroll") for (int m = 0; m < 4; ++m) \
      _Pragma("unroll") for (int n = 0; n < 4; ++n) \
        acc[m][n] = __builtin_amdgcn_mfma_f32_16x16x32_bf16(a[m], b[n], acc[m][n], 0, 0, 0); \
  } }

  G2_ISSA(0, A0lds); SB0;
  G2_LOADB(0, 0);
  G2_LOADB(1, 1);
  G2_CVTW(0, B0lds);
  WAITBAR8;

  #pragma unroll 1
  for (int kq = 0; kq + 4 <= NK2; kq += 2) {
    G2_ISSA(kq + 1, A1lds); SB0;
    G2_LOADB(0, kq + 2);
    G2_MFMA(A0lds, B0lds);
    G2_CVTW(1, B1lds);
    WAITBAR8;
    G2_ISSA(kq + 2, A0lds); SB0;
    G2_LOADB(1, kq + 3);
    G2_MFMA(A1lds, B1lds);
    G2_CVTW(0, B0lds);
    WAITBAR8;
  }
  G2_ISSA(NK2 - 1, A1lds); SB0;
  G2_MFMA(A0lds, B0lds);
  G2_CVTW(1, B1lds);
  WAITBAR0;
  G2_MFMA(A1lds, B1lds);

  #pragma unroll
  for (int m = 0; m < 4; ++m) {
    #pragma unroll
    for (int r = 0; r < 4; ++r) {
      int row = wr + m * 16 + g4 * 4 + r;
      if (m0 + row < cntE) {
        float* orow = pbuf + (size_t)(base + m0 + row) * H_DIM + n0 + wc;
        #pragma unroll
        for (int n = 0; n < 4; ++n)
          orow[n * 16 + ln15] = acc[m][n][r];
      }
    }
  }
#undef G2_ISSA
#undef G2_LOADB
#undef G2_CVTW
#undef G2_MFMA
}

// ---------- combine: out[t] = sum_k pbuf[ppos[t][k]] ----------
__global__ __launch_bounds__(256) void combine_kernel(const float* __restrict__ pbuf,
                                                      const int* __restrict__ ppos,
                                                      float* __restrict__ out) {
  int idx = blockIdx.x * 256 + threadIdx.x;
  int t = idx >> 9;
  int h4 = (idx & 511) * 4;
  int4 pp = ((const int4*)ppos)[t];
  float4 s0 = *(const float4*)&pbuf[(size_t)pp.x * H_DIM + h4];
  float4 s1 = *(const float4*)&pbuf[(size_t)pp.y * H_DIM + h4];
  float4 s2 = *(const float4*)&pbuf[(size_t)pp.z * H_DIM + h4];
  float4 s3 = *(const float4*)&pbuf[(size_t)pp.w * H_DIM + h4];
  float4 o;
  o.x = s0.x + s1.x + s2.x + s3.x;
  o.y = s0.y + s1.y + s2.y + s3.y;
  o.z = s0.z + s1.z + s2.z + s3.z;
  o.w = s0.w + s1.w + s2.w + s3.w;
  *(float4*)&out[(size_t)t * H_DIM + h4] = o;
}

// ---------- launch ----------
extern "C" void kernel_launch(void* const* d_in, const int* in_sizes, int n_in,
                              void* d_out, int out_size, void* d_ws, size_t ws_size,
                              hipStream_t stream) {
  (void)in_sizes; (void)n_in; (void)out_size;
  if (ws_size < WS_NEED) return;

  const float* x  = (const float*)d_in[0];
  const float* rw = (const float*)d_in[1];
  const float* wg = (const float*)d_in[2];
  const float* wu = (const float*)d_in[3];
  const float* wd = (const float*)d_in[4];
  float* out = (float*)d_out;
  float* logits = out + (size_t)T_TOK * H_DIM;

  char* ws = (char*)d_ws;
  u16* xb    = (u16*)(ws + OFF_XB);
  u16* abuf  = (u16*)(ws + OFF_ABUF);
  float* pbuf = (float*)(ws + OFF_PBUF);
  int* sel   = (int*)(ws + OFF_SEL);
  float* wts = (float*)(ws + OFF_WTS);
  int* cnt   = (int*)(ws + OFF_CNT);
  int* offs  = (int*)(ws + OFF_OFFS);
  int* curs  = (int*)(ws + OFF_CURS);
  int* rtok  = (int*)(ws + OFF_RTOK);
  float* rwt = (float*)(ws + OFF_RWT);
  int* ppos  = (int*)(ws + OFF_PPOS);

  hipMemsetAsync(ws + OFF_CNT, 0, 128, stream);

  cvt_x_kernel<<<(T_TOK * H_DIM / 8) / 256, 256, 0, stream>>>(x, xb);
  router_kernel<<<T_TOK / 4, 256, 0, stream>>>(x, rw, logits, sel, wts);
  hist_kernel<<<(T_TOK * TOPK) / 256, 256, 0, stream>>>(sel, cnt);
  prefix_kernel<<<1, 64, 0, stream>>>(cnt, offs, curs);
  scatter_kernel<<<(T_TOK * TOPK) / 256, 256, 0, stream>>>(sel, wts, curs, rtok, rwt, ppos);
  gemm1_kernel<<<dim3(I_DIM / 64, 16, E_NUM), 256, 0, stream>>>(xb, wg, wu, cnt, offs, rtok, rwt, abuf);
  gemm2_kernel<<<dim3(H_DIM / 128, 16, E_NUM), 256, 0, stream>>>(abuf, wd, cnt, offs, pbuf);
  combine_kernel<<<(T_TOK * (H_DIM / 4)) / 256, 256, 0, stream>>>(pbuf, ppos, out);
}